// Round 15
// baseline (328.559 us; speedup 1.0000x reference)
//
#include <hip/hip_runtime.h>
#include <stdint.h>

typedef unsigned short u16;
typedef unsigned int   u32;
typedef __attribute__((ext_vector_type(8))) __bf16 bf16x8;
typedef __attribute__((ext_vector_type(4))) float  f32x4;
typedef __attribute__((ext_vector_type(4))) short  s16x4;

#define NB  64
#define NQ  784
#define NK  196
#define NKP 208      // nk padded to 13*16
#define DM  512

static __device__ inline u16 f2bf(float f) {
  u32 u = __float_as_uint(f);
  u32 r = (u + 0x7fffu + ((u >> 16) & 1u)) >> 16;
  return (u16)r;
}

static __device__ inline bf16x8 ld8(const u16* p) {
  return *reinterpret_cast<const bf16x8*>(p);
}
static __device__ inline f32x4 mfma16(bf16x8 a, bf16x8 b, f32x4 c) {
  return __builtin_amdgcn_mfma_f32_16x16x32_bf16(a, b, c, 0, 0, 0);
}
// K=16 bf16 MFMA (4 bf16 per lane per operand)
static __device__ inline f32x4 mfma16k16(s16x4 a, s16x4 b, f32x4 c) {
#if __has_builtin(__builtin_amdgcn_mfma_f32_16x16x16bf16_1k)
  return __builtin_amdgcn_mfma_f32_16x16x16bf16_1k(a, b, c, 0, 0, 0);
#elif __has_builtin(__builtin_amdgcn_mfma_f32_16x16x16_bf16)
  typedef __attribute__((ext_vector_type(4))) __bf16 bf16x4_t;
  union { s16x4 s; bf16x4_t b; } ua, ub;
  ua.s = a; ub.s = b;
  return __builtin_amdgcn_mfma_f32_16x16x16_bf16(ua.b, ub.b, c, 0, 0, 0);
#else
  asm volatile("v_mfma_f32_16x16x16_bf16 %0, %1, %2, %0\n\ts_nop 7\n\ts_nop 7"
               : "+v"(c) : "v"(a), "v"(b));
  return c;
#endif
}

// wave-uniform float -> SGPR
static __device__ inline float sgpr_f(float x) {
  return __uint_as_float(__builtin_amdgcn_readfirstlane(__float_as_uint(x)));
}

// async global -> LDS, 16B per lane; LDS dest must be wave-uniform base
static __device__ inline void gl_lds16(const void* g, void* l) {
  __builtin_amdgcn_global_load_lds(
      (const __attribute__((address_space(1))) void*)g,
      (__attribute__((address_space(3))) void*)l, 16, 0, 0);
}

// ---------------- fp32 -> bf16 conversion (weights) ----------------
__global__ __launch_bounds__(256) void cvt_kernel(const float* __restrict__ in,
                                                  u16* __restrict__ out, int n) {
  int i = (blockIdx.x * 256 + threadIdx.x) * 4;
  if (i + 3 < n) {
    float4 f = *reinterpret_cast<const float4*>(in + i);
    ushort4 o;
    o.x = f2bf(f.x); o.y = f2bf(f.y); o.z = f2bf(f.z); o.w = f2bf(f.w);
    *reinterpret_cast<ushort4*>(out + i) = o;
  }
}

// ---------------- fused queries cvt (fp32->bf16) + spatial-reduce LayerNorm ------------
__global__ __launch_bounds__(256) void cvtln_kernel(const float* __restrict__ q,
                                                    const float* __restrict__ sr_w,
                                                    const float* __restrict__ sr_b,
                                                    const float* __restrict__ ln_w,
                                                    const float* __restrict__ ln_b,
                                                    u16* __restrict__ qbf,
                                                    u16* __restrict__ xln) {
  int w = blockIdx.x * 4 + (threadIdx.x >> 6);
  int lane = threadIdx.x & 63;
  if (w >= NB * NQ) {
    int w2 = w - NB * NQ;
    if (w2 < NB * 12) {
      int b = w2 / 12, pr = w2 % 12;
      u16* outp = xln + ((size_t)(b * NKP + NK + pr)) * DM;
      *reinterpret_cast<uint4*>(outp + lane * 8) = make_uint4(0u, 0u, 0u, 0u);
    }
    return;
  }
  int b = w / NQ, n = w % NQ;
  const float* row = q + ((size_t)w) * DM;
  int c0 = lane * 4, c1 = 256 + lane * 4;
  float4 x0 = *reinterpret_cast<const float4*>(row + c0);
  float4 x1 = *reinterpret_cast<const float4*>(row + c1);
  u16* qp = qbf + (size_t)w * DM;
  ushort4 q0, q1;
  q0.x = f2bf(x0.x); q0.y = f2bf(x0.y); q0.z = f2bf(x0.z); q0.w = f2bf(x0.w);
  q1.x = f2bf(x1.x); q1.y = f2bf(x1.y); q1.z = f2bf(x1.z); q1.w = f2bf(x1.w);
  *reinterpret_cast<ushort4*>(qp + c0) = q0;
  *reinterpret_cast<ushort4*>(qp + c1) = q1;
  int y = n / 28, x = n % 28;
  if ((y & 1) | (x & 1)) return;
  int np = (y >> 1) * 14 + (x >> 1);
  float4 w0 = *reinterpret_cast<const float4*>(sr_w + c0);
  float4 w1 = *reinterpret_cast<const float4*>(sr_w + c1);
  float4 s0 = *reinterpret_cast<const float4*>(sr_b + c0);
  float4 s1 = *reinterpret_cast<const float4*>(sr_b + c1);
  float yv[8];
  yv[0] = x0.x * w0.x + s0.x; yv[1] = x0.y * w0.y + s0.y;
  yv[2] = x0.z * w0.z + s0.z; yv[3] = x0.w * w0.w + s0.w;
  yv[4] = x1.x * w1.x + s1.x; yv[5] = x1.y * w1.y + s1.y;
  yv[6] = x1.z * w1.z + s1.z; yv[7] = x1.w * w1.w + s1.w;
  float s = 0.f, ss = 0.f;
  #pragma unroll
  for (int i = 0; i < 8; i++) { s += yv[i]; ss += yv[i] * yv[i]; }
  #pragma unroll
  for (int off = 1; off < 64; off <<= 1) {
    s += __shfl_xor(s, off); ss += __shfl_xor(ss, off);
  }
  float mu = s * (1.f / 512.f);
  float var = ss * (1.f / 512.f) - mu * mu;
  float rs = rsqrtf(var + 1e-5f);
  float4 lw0 = *reinterpret_cast<const float4*>(ln_w + c0);
  float4 lw1 = *reinterpret_cast<const float4*>(ln_w + c1);
  float4 lb0 = *reinterpret_cast<const float4*>(ln_b + c0);
  float4 lb1 = *reinterpret_cast<const float4*>(ln_b + c1);
  ushort4 o0, o1;
  o0.x = f2bf((yv[0] - mu) * rs * lw0.x + lb0.x);
  o0.y = f2bf((yv[1] - mu) * rs * lw0.y + lb0.y);
  o0.z = f2bf((yv[2] - mu) * rs * lw0.z + lb0.z);
  o0.w = f2bf((yv[3] - mu) * rs * lw0.w + lb0.w);
  o1.x = f2bf((yv[4] - mu) * rs * lw1.x + lb1.x);
  o1.y = f2bf((yv[5] - mu) * rs * lw1.y + lb1.y);
  o1.z = f2bf((yv[6] - mu) * rs * lw1.z + lb1.z);
  o1.w = f2bf((yv[7] - mu) * rs * lw1.w + lb1.w);
  u16* outp = xln + ((size_t)(b * NKP + np)) * DM;
  *reinterpret_cast<ushort4*>(outp + c0) = o0;
  *reinterpret_cast<ushort4*>(outp + c1) = o1;
}

// ---------------- shared GEMM body: C[M,512] = A[M,512]*W[512,512]^T + bias ------------
template <int OMODE>
static __device__ __forceinline__ void gemm_body(const u16* __restrict__ A,
                                                 const u16* __restrict__ Bw,
                                                 const float* __restrict__ bias,
                                                 void* __restrict__ Cptr,
                                                 int nt, int mt,
                                                 u16* Al0, u16* Al1,
                                                 u16* Bl0, u16* Bl1) {
  int wv = threadIdx.x >> 6, lane = threadIdx.x & 63;
  int lr = lane & 15, lg = lane >> 4;
  int wr = wv >> 1, wc = wv & 1;
  int row0 = mt * 128, col0 = nt * 128;

  auto stage = [&](int kk, int bi) {
    u16* Al = bi ? Al1 : Al0;
    u16* Bl = bi ? Bl1 : Bl0;
    #pragma unroll
    for (int i = 0; i < 4; i++) {
      int t = wv * 4 + i;                    // 0..15
      int rr = (t & 7) * 16 + (lane >> 2);
      int cc = lane & 3;
      if (t < 8) {
        gl_lds16(A + (size_t)(row0 + rr) * DM + kk + cc * 8, (char*)Al + t * 1024);
      } else {
        gl_lds16(Bw + (size_t)(col0 + rr) * DM + kk + cc * 8, (char*)Bl + (t - 8) * 1024);
      }
    }
  };

  f32x4 acc[4][4] = {};
  stage(0, 0);
  __syncthreads();
  for (int s = 0; s < 16; s++) {
    int bi = s & 1;
    if (s < 15) stage((s + 1) * 32, bi ^ 1);
    u16* Al = bi ? Al1 : Al0;
    u16* Bl = bi ? Bl1 : Bl0;
    bf16x8 am[4], bn[4];
    #pragma unroll
    for (int m = 0; m < 4; m++)
      am[m] = ld8(Al + (wr * 64 + m * 16 + lr) * 32 + lg * 8);
    #pragma unroll
    for (int n = 0; n < 4; n++)
      bn[n] = ld8(Bl + (wc * 64 + n * 16 + lr) * 32 + lg * 8);
    #pragma unroll
    for (int m = 0; m < 4; m++)
      #pragma unroll
      for (int n = 0; n < 4; n++)
        acc[m][n] = mfma16(am[m], bn[n], acc[m][n]);
    __syncthreads();
  }
  if (OMODE == 2) {
    #pragma unroll
    for (int n = 0; n < 4; n++) {
      int col = col0 + wc * 64 + n * 16 + lr;
      float bs = bias[col];
      #pragma unroll
      for (int m = 0; m < 4; m++) {
        int rbase = row0 + wr * 64 + m * 16 + lg * 4;
        int bb = rbase / NKP;
        int kr = rbase % NKP;          // kr&15 == lg*4
        ushort4 o4;
        o4.x = f2bf(acc[m][n][0] + bs);
        o4.y = f2bf(acc[m][n][1] + bs);
        o4.z = f2bf(acc[m][n][2] + bs);
        o4.w = f2bf(acc[m][n][3] + bs);
        size_t dst = (((size_t)bb * 13 + (kr >> 4)) * 512 + col) * 16 + (kr & 15);
        *reinterpret_cast<ushort4*>(&((u16*)Cptr)[dst]) = o4;
      }
    }
  } else {
    #pragma unroll
    for (int n = 0; n < 4; n++) {
      int col = col0 + wc * 64 + n * 16 + lr;
      float bs = bias[col];
      #pragma unroll
      for (int m = 0; m < 4; m++) {
        #pragma unroll
        for (int r = 0; r < 4; r++) {
          int row = row0 + wr * 64 + m * 16 + lg * 4 + r;
          float v = acc[m][n][r] + bs;
          if (OMODE == 0) {
            ((u16*)Cptr)[(size_t)row * DM + col] = f2bf(v);
          } else {
            ((float*)Cptr)[(size_t)row * DM + col] = v;
          }
        }
      }
    }
  }
}

template <int OMODE>
__global__ __launch_bounds__(256) void gemm2_kernel(const u16* __restrict__ A,
                                                    const u16* __restrict__ Bw,
                                                    const float* __restrict__ bias,
                                                    void* __restrict__ Cptr) {
  __shared__ __align__(16) u16 Al[2][128 * 32];
  __shared__ __align__(16) u16 Bl[2][128 * 32];
  gemm_body<OMODE>(A, Bw, bias, Cptr, blockIdx.x, blockIdx.y,
                   &Al[0][0], &Al[1][0], &Bl[0][0], &Bl[1][0]);
}

// fused K-proj (OMODE 0) + V-proj (OMODE 2): blockIdx.z selects.
__global__ __launch_bounds__(256) void kvgemm_kernel(const u16* __restrict__ A,
                                                     const u16* __restrict__ Wk,
                                                     const float* __restrict__ bk,
                                                     void* __restrict__ Kout,
                                                     const u16* __restrict__ Wv,
                                                     const float* __restrict__ bv,
                                                     void* __restrict__ Vout) {
  __shared__ __align__(16) u16 Al[2][128 * 32];
  __shared__ __align__(16) u16 Bl[2][128 * 32];
  if (blockIdx.z == 0) {
    gemm_body<0>(A, Wk, bk, Kout, blockIdx.x, blockIdx.y,
                 &Al[0][0], &Al[1][0], &Bl[0][0], &Bl[1][0]);
  } else {
    gemm_body<2>(A, Wv, bv, Vout, blockIdx.x, blockIdx.y,
                 &Al[0][0], &Al[1][0], &Bl[0][0], &Bl[1][0]);
  }
}

// ---------------- fused attn: de-duplicated QK^T via LDS score exchange ----------------
// grid 1600 XCD-clustered (id%8 == b%8), 4 waves, 32 q-rows (2 tiles) per block.
// Phase structure (2 barriers):
//   1st half: wave wv computes QK^T for ONLY its 2 raw heads {2wv,2wv+1}
//             (Q fragments register-resident, 32 VGPR; 4 kf ds_reads, 8 MFMA),
//             writes raw fp32 score tiles to s2[t][h] (64 lanes x 16B = full
//             1KB tile -> bank-optimal, write/read use identical offsets).
//   -- barrier -- (scores visible; nothing in vmcnt)
//   2nd half: stage K(kt+1) + early-V loads; each wave reads all 8 heads'
//             scores (16 ds_reads), mixes for its 2 OUTPUT heads, exp
//             (no-max softmax, scores data-bounded), packs unnormalized bf16
//             P, PV MFMA. -- barrier -- (stage drained, s2/Kl reusable).
// Eliminates the 4x redundant QK^T of round 14: per-wave LDS ops 48 -> 24,
// QK^T MFMA 32 -> 8. LDS 64KB -> 48KB (3 blocks/CU).
__global__ __launch_bounds__(256) void attn_kernel(const u16* __restrict__ Q,
                                                   const u16* __restrict__ K,
                                                   const u16* __restrict__ VTt,
                                                   const float* __restrict__ tw,
                                                   u16* __restrict__ Oat) {
  __shared__ __align__(16) u16 Kl[2][16 * 512];   // 2 x 16KB, chunk-major
  __shared__ __align__(16) float s2[2 * 8 * 256]; // 16KB raw scores [t][h][16q][16k]
  int i = blockIdx.x;
  int g8 = i & 7;            // XCD group == b%8
  int j = i >> 3;            // 0..199
  int qc = j % 25;
  int b = g8 + 8 * (j / 25);
  int tid = threadIdx.x, wv = tid >> 6, lane = tid & 63;
  int lr = lane & 15, lg = lane >> 4;
  int q0A = qc * 32;
  int q0B = (qc < 24) ? (q0A + 16) : q0A;   // tail duplicates tile A
  int g0 = wv * 2;           // this wave's raw-head pair AND output-head pair

  const u16* Kb = K + (size_t)b * NKP * DM;
  const u16* Vtb = VTt + (size_t)b * 13 * 8192;

  // wave-uniform mixing weights -> SGPRs (1/sqrt(64) folded)
  float w0[8], w1[8];
  #pragma unroll
  for (int h = 0; h < 8; h++) {
    w0[h] = sgpr_f(tw[(g0 + 0) * 8 + h] * 0.125f);
    w1[h] = sgpr_f(tw[(g0 + 1) * 8 + h] * 0.125f);
  }

  // Q fragments REGISTER-resident: only this wave's 2 raw heads x 2 tiles.
  // B-operand layout: lane holds q-row = lr, d = h*64 + half*32 + lg*8.
  bf16x8 qr[2][2][2];   // [tile][hh][half]
  #pragma unroll
  for (int t = 0; t < 2; t++) {
    const u16* Qb = Q + ((size_t)b * NQ + (t ? q0B : q0A)) * DM;
    #pragma unroll
    for (int hh = 0; hh < 2; hh++) {
      qr[t][hh][0] = ld8(Qb + (size_t)lr * DM + (g0 + hh) * 64 + lg * 8);
      qr[t][hh][1] = ld8(Qb + (size_t)lr * DM + (g0 + hh) * 64 + 32 + lg * 8);
    }
  }

  // chunk-major staging: slot s = g*64+lane -> (c = g*4 + lane>>4, r = lane&15)
  auto stageK = [&](int kt, int bi) {
    #pragma unroll
    for (int i2 = 0; i2 < 4; i2++) {
      int g = wv * 4 + i2;
      gl_lds16(Kb + (size_t)(kt * 16 + (lane & 15)) * DM + (g * 4 + (lane >> 4)) * 8,
               (char*)&Kl[bi][0] + g * 1024);
    }
  };
  stageK(0, 0);
  __syncthreads();

  f32x4 o[2][2][4] = {};      // [tile][g][j]
  float sumA0 = 0.f, sumA1 = 0.f, sumB0 = 0.f, sumB1 = 0.f;

  for (int kt = 0; kt < 13; kt++) {
    int bi = kt & 1;
    const u16* kbase = &Kl[bi][0] + lg * 128 + lr * 8;

    // ---- 1st half: QK^T for this wave's 2 raw heads, both tiles ----
    f32x4 sc[2][2];   // [tile][hh]
    #pragma unroll
    for (int hh = 0; hh < 2; hh++) {
      bf16x8 kf0 = ld8(kbase + (g0 + hh) * 1024);
      bf16x8 kf1 = ld8(kbase + (g0 + hh) * 1024 + 512);
      #pragma unroll
      for (int t = 0; t < 2; t++) {
        f32x4 tt = {0.f, 0.f, 0.f, 0.f};
        tt = mfma16(kf0, qr[t][hh][0], tt);
        tt = mfma16(kf1, qr[t][hh][1], tt);
        sc[t][hh] = tt;
      }
    }
    // write raw scores: lane (q=lr, k=lg*4..+3) -> float offset lr*16 + lg*4
    #pragma unroll
    for (int t = 0; t < 2; t++)
      #pragma unroll
      for (int hh = 0; hh < 2; hh++)
        *reinterpret_cast<f32x4*>(s2 + (t * 8 + g0 + hh) * 256 + lr * 16 + lg * 4) =
            sc[t][hh];
    __syncthreads();   // scores visible to all waves

    // ---- 2nd half: stage next K + early V, then mix/exp/PV ----
    if (kt < 12) stageK(kt + 1, bi ^ 1);
    s16x4 vb[2][4];
    #pragma unroll
    for (int gi = 0; gi < 2; gi++) {
      #pragma unroll
      for (int j2 = 0; j2 < 4; j2++) {
        int d = (g0 + gi) * 64 + j2 * 16 + lr;
        vb[gi][j2] = *reinterpret_cast<const s16x4*>(
            Vtb + (size_t)kt * 8192 + d * 16 + lg * 4);
      }
    }

    bool masked = (kt == 12) && (lg != 0);   // k >= 196
    s16x4 pa[2][2];
    #pragma unroll
    for (int t = 0; t < 2; t++) {
      f32x4 sa = {0.f, 0.f, 0.f, 0.f};
      f32x4 sb = {0.f, 0.f, 0.f, 0.f};
      #pragma unroll
      for (int h = 0; h < 8; h++) {
        f32x4 scv = *reinterpret_cast<const f32x4*>(
            s2 + (t * 8 + h) * 256 + lr * 16 + lg * 4);
        sa += scv * w0[h];
        sb += scv * w1[h];
      }
      float e0 = masked ? 0.f : __expf(sa[0]);
      float e1 = masked ? 0.f : __expf(sa[1]);
      float e2 = masked ? 0.f : __expf(sa[2]);
      float e3 = masked ? 0.f : __expf(sa[3]);
      float f0 = masked ? 0.f : __expf(sb[0]);
      float f1 = masked ? 0.f : __expf(sb[1]);
      float f2 = masked ? 0.f : __expf(sb[2]);
      float f3 = masked ? 0.f : __expf(sb[3]);
      if (t == 0) {
        sumA0 += (e0 + e1) + (e2 + e3);
        sumA1 += (f0 + f1) + (f2 + f3);
      } else {
        sumB0 += (e0 + e1) + (e2 + e3);
        sumB1 += (f0 + f1) + (f2 + f3);
      }
      union { __bf16 e[4]; s16x4 sv; } pk;
      pk.e[0] = (__bf16)e0; pk.e[1] = (__bf16)e1;
      pk.e[2] = (__bf16)e2; pk.e[3] = (__bf16)e3;
      pa[t][0] = pk.sv;
      pk.e[0] = (__bf16)f0; pk.e[1] = (__bf16)f1;
      pk.e[2] = (__bf16)f2; pk.e[3] = (__bf16)f3;
      pa[t][1] = pk.sv;
    }

    // PV: both tiles share vb
    __builtin_amdgcn_s_setprio(1);
    #pragma unroll
    for (int t = 0; t < 2; t++) {
      #pragma unroll
      for (int gi = 0; gi < 2; gi++) {
        #pragma unroll
        for (int j2 = 0; j2 < 4; j2++)
          o[t][gi][j2] = mfma16k16(pa[t][gi], vb[gi][j2], o[t][gi][j2]);
      }
    }
    __builtin_amdgcn_s_setprio(0);
    __syncthreads();   // stage(kt+1) drained; s2/Kl[bi] reusable next phase
  }

  // complete row sums (k split across lane groups 16 apart)
  sumA0 += __shfl_xor(sumA0, 16); sumA0 += __shfl_xor(sumA0, 32);
  sumA1 += __shfl_xor(sumA1, 16); sumA1 += __shfl_xor(sumA1, 32);
  sumB0 += __shfl_xor(sumB0, 16); sumB0 += __shfl_xor(sumB0, 32);
  sumB1 += __shfl_xor(sumB1, 16); sumB1 += __shfl_xor(sumB1, 32);
  float ivA0 = 1.0f / sumA0, ivA1 = 1.0f / sumA1;
  float ivB0 = 1.0f / sumB0, ivB1 = 1.0f / sumB1;
  #pragma unroll
  for (int t = 0; t < 2; t++) {
    if (t == 1 && qc == 24) break;   // tail: tile B is a duplicate
    int q0 = t ? q0B : q0A;
    #pragma unroll
    for (int gi = 0; gi < 2; gi++) {
      int g = g0 + gi;
      float ivsrc = t ? (gi ? ivB1 : ivB0) : (gi ? ivA1 : ivA0);
      #pragma unroll
      for (int r = 0; r < 4; r++) {
        int q = lg * 4 + r;
        float iv = __shfl(ivsrc, q);   // sum lives at lane lr == q
        #pragma unroll
        for (int j2 = 0; j2 < 4; j2++) {
          Oat[((size_t)(b * NQ + q0 + q)) * DM + g * 64 + j2 * 16 + lr] =
              f2bf(o[t][gi][j2][r] * iv);
        }
      }
    }
  }
}

// ---------------- launch ----------------
extern "C" void kernel_launch(void* const* d_in, const int* in_sizes, int n_in,
                              void* d_out, int out_size, void* d_ws, size_t ws_size,
                              hipStream_t stream) {
  const float* queries = (const float*)d_in[0];
  const float* Wq = (const float*)d_in[3];
  const float* bq = (const float*)d_in[4];
  const float* Wk = (const float*)d_in[5];
  const float* bk = (const float*)d_in[6];
  const float* Wv = (const float*)d_in[7];
  const float* bv = (const float*)d_in[8];
  const float* Wo = (const float*)d_in[9];
  const float* bo = (const float*)d_in[10];
  const float* sr_w = (const float*)d_in[11];
  const float* sr_b = (const float*)d_in[12];
  const float* ln_w = (const float*)d_in[13];
  const float* ln_b = (const float*)d_in[14];
  const float* tw = (const float*)d_in[15];

  char* ws = (char*)d_ws;
  u16* wq_bf = (u16*)(ws + 0);          // 512KB
  u16* wk_bf = (u16*)(ws + 524288);
  u16* wv_bf = (u16*)(ws + 1048576);
  u16* wo_bf = (u16*)(ws + 1572864);
  u16* xln   = (u16*)(ws + 2097152);    // 64*208*512*2 = 13,631,488
  u16* Kbuf  = (u16*)(ws + 15728640);   // 13,631,488
  u16* VTt   = (u16*)(ws + 29360128);   // 64*13*512*16*2 = 13,631,488
  u16* Qbuf  = (u16*)(ws + 42991616);   // 64*784*512*2 = 51,380,224
  u16* qbf   = (u16*)(ws + 94371840);   // 51,380,224 -> end 145,752,064
  u16* Oat   = qbf;                     // qbf dead after Q-proj; attn reuses it
  if (ws_size < 145752064u) return;     // fail loudly (output stays poisoned)

  const int NW = 262144;  // 512*512
  cvt_kernel<<<256, 256, 0, stream>>>(Wq, wq_bf, NW);
  cvt_kernel<<<256, 256, 0, stream>>>(Wk, wk_bf, NW);
  cvt_kernel<<<256, 256, 0, stream>>>(Wv, wv_bf, NW);
  cvt_kernel<<<256, 256, 0, stream>>>(Wo, wo_bf, NW);

  // fused queries cvt + LN: 64*784 + 64*12 waves
  cvtln_kernel<<<(NB * NQ + NB * 12 + 3) / 4, 256, 0, stream>>>(
      queries, sr_w, sr_b, ln_w, ln_b, qbf, xln);

  // Q = qbf @ Wq^T + bq   M = 50176
  gemm2_kernel<0><<<dim3(4, 392), 256, 0, stream>>>(qbf, wq_bf, bq, Qbuf);
  // K-proj + V-proj fused (z=0: K [row][col] bf16; z=1: V tiled)
  kvgemm_kernel<<<dim3(4, 104, 2), 256, 0, stream>>>(xln, wk_bf, bk, Kbuf,
                                                     wv_bf, bv, VTt);

  attn_kernel<<<dim3(1600), 256, 0, stream>>>(Qbuf, Kbuf, VTt, tw, Oat);

  // out = Oat @ Wo^T + bo  (fp32 out)
  gemm2_kernel<1><<<dim3(4, 392), 256, 0, stream>>>(Oat, wo_bf, bo, d_out);
}

// Round 16
// 317.620 us; speedup vs baseline: 1.0344x; 1.0344x over previous
//
#include <hip/hip_runtime.h>
#include <stdint.h>

typedef unsigned short u16;
typedef unsigned int   u32;
typedef __attribute__((ext_vector_type(8))) __bf16 bf16x8;
typedef __attribute__((ext_vector_type(4))) float  f32x4;
typedef __attribute__((ext_vector_type(4))) short  s16x4;

#define NB  64
#define NQ  784
#define NK  196
#define NKP 208      // nk padded to 13*16
#define DM  512

static __device__ inline u16 f2bf(float f) {
  u32 u = __float_as_uint(f);
  u32 r = (u + 0x7fffu + ((u >> 16) & 1u)) >> 16;
  return (u16)r;
}

static __device__ inline bf16x8 ld8(const u16* p) {
  return *reinterpret_cast<const bf16x8*>(p);
}
static __device__ inline f32x4 mfma16(bf16x8 a, bf16x8 b, f32x4 c) {
  return __builtin_amdgcn_mfma_f32_16x16x32_bf16(a, b, c, 0, 0, 0);
}
// K=16 bf16 MFMA (4 bf16 per lane per operand)
static __device__ inline f32x4 mfma16k16(s16x4 a, s16x4 b, f32x4 c) {
#if __has_builtin(__builtin_amdgcn_mfma_f32_16x16x16bf16_1k)
  return __builtin_amdgcn_mfma_f32_16x16x16bf16_1k(a, b, c, 0, 0, 0);
#elif __has_builtin(__builtin_amdgcn_mfma_f32_16x16x16_bf16)
  typedef __attribute__((ext_vector_type(4))) __bf16 bf16x4_t;
  union { s16x4 s; bf16x4_t b; } ua, ub;
  ua.s = a; ub.s = b;
  return __builtin_amdgcn_mfma_f32_16x16x16_bf16(ua.b, ub.b, c, 0, 0, 0);
#else
  asm volatile("v_mfma_f32_16x16x16_bf16 %0, %1, %2, %0\n\ts_nop 7\n\ts_nop 7"
               : "+v"(c) : "v"(a), "v"(b));
  return c;
#endif
}

// wave-uniform float -> SGPR
static __device__ inline float sgpr_f(float x) {
  return __uint_as_float(__builtin_amdgcn_readfirstlane(__float_as_uint(x)));
}

// async global -> LDS, 16B per lane; LDS dest must be wave-uniform base
static __device__ inline void gl_lds16(const void* g, void* l) {
  __builtin_amdgcn_global_load_lds(
      (const __attribute__((address_space(1))) void*)g,
      (__attribute__((address_space(3))) void*)l, 16, 0, 0);
}

// ---------------- fp32 -> bf16 conversion (weights) ----------------
__global__ __launch_bounds__(256) void cvt_kernel(const float* __restrict__ in,
                                                  u16* __restrict__ out, int n) {
  int i = (blockIdx.x * 256 + threadIdx.x) * 4;
  if (i + 3 < n) {
    float4 f = *reinterpret_cast<const float4*>(in + i);
    ushort4 o;
    o.x = f2bf(f.x); o.y = f2bf(f.y); o.z = f2bf(f.z); o.w = f2bf(f.w);
    *reinterpret_cast<ushort4*>(out + i) = o;
  }
}

// ---------------- fused queries cvt (fp32->bf16) + spatial-reduce LayerNorm ------------
__global__ __launch_bounds__(256) void cvtln_kernel(const float* __restrict__ q,
                                                    const float* __restrict__ sr_w,
                                                    const float* __restrict__ sr_b,
                                                    const float* __restrict__ ln_w,
                                                    const float* __restrict__ ln_b,
                                                    u16* __restrict__ qbf,
                                                    u16* __restrict__ xln) {
  int w = blockIdx.x * 4 + (threadIdx.x >> 6);
  int lane = threadIdx.x & 63;
  if (w >= NB * NQ) {
    int w2 = w - NB * NQ;
    if (w2 < NB * 12) {
      int b = w2 / 12, pr = w2 % 12;
      u16* outp = xln + ((size_t)(b * NKP + NK + pr)) * DM;
      *reinterpret_cast<uint4*>(outp + lane * 8) = make_uint4(0u, 0u, 0u, 0u);
    }
    return;
  }
  int b = w / NQ, n = w % NQ;
  const float* row = q + ((size_t)w) * DM;
  int c0 = lane * 4, c1 = 256 + lane * 4;
  float4 x0 = *reinterpret_cast<const float4*>(row + c0);
  float4 x1 = *reinterpret_cast<const float4*>(row + c1);
  u16* qp = qbf + (size_t)w * DM;
  ushort4 q0, q1;
  q0.x = f2bf(x0.x); q0.y = f2bf(x0.y); q0.z = f2bf(x0.z); q0.w = f2bf(x0.w);
  q1.x = f2bf(x1.x); q1.y = f2bf(x1.y); q1.z = f2bf(x1.z); q1.w = f2bf(x1.w);
  *reinterpret_cast<ushort4*>(qp + c0) = q0;
  *reinterpret_cast<ushort4*>(qp + c1) = q1;
  int y = n / 28, x = n % 28;
  if ((y & 1) | (x & 1)) return;
  int np = (y >> 1) * 14 + (x >> 1);
  float4 w0 = *reinterpret_cast<const float4*>(sr_w + c0);
  float4 w1 = *reinterpret_cast<const float4*>(sr_w + c1);
  float4 s0 = *reinterpret_cast<const float4*>(sr_b + c0);
  float4 s1 = *reinterpret_cast<const float4*>(sr_b + c1);
  float yv[8];
  yv[0] = x0.x * w0.x + s0.x; yv[1] = x0.y * w0.y + s0.y;
  yv[2] = x0.z * w0.z + s0.z; yv[3] = x0.w * w0.w + s0.w;
  yv[4] = x1.x * w1.x + s1.x; yv[5] = x1.y * w1.y + s1.y;
  yv[6] = x1.z * w1.z + s1.z; yv[7] = x1.w * w1.w + s1.w;
  float s = 0.f, ss = 0.f;
  #pragma unroll
  for (int i = 0; i < 8; i++) { s += yv[i]; ss += yv[i] * yv[i]; }
  #pragma unroll
  for (int off = 1; off < 64; off <<= 1) {
    s += __shfl_xor(s, off); ss += __shfl_xor(ss, off);
  }
  float mu = s * (1.f / 512.f);
  float var = ss * (1.f / 512.f) - mu * mu;
  float rs = rsqrtf(var + 1e-5f);
  float4 lw0 = *reinterpret_cast<const float4*>(ln_w + c0);
  float4 lw1 = *reinterpret_cast<const float4*>(ln_w + c1);
  float4 lb0 = *reinterpret_cast<const float4*>(ln_b + c0);
  float4 lb1 = *reinterpret_cast<const float4*>(ln_b + c1);
  ushort4 o0, o1;
  o0.x = f2bf((yv[0] - mu) * rs * lw0.x + lb0.x);
  o0.y = f2bf((yv[1] - mu) * rs * lw0.y + lb0.y);
  o0.z = f2bf((yv[2] - mu) * rs * lw0.z + lb0.z);
  o0.w = f2bf((yv[3] - mu) * rs * lw0.w + lb0.w);
  o1.x = f2bf((yv[4] - mu) * rs * lw1.x + lb1.x);
  o1.y = f2bf((yv[5] - mu) * rs * lw1.y + lb1.y);
  o1.z = f2bf((yv[6] - mu) * rs * lw1.z + lb1.z);
  o1.w = f2bf((yv[7] - mu) * rs * lw1.w + lb1.w);
  u16* outp = xln + ((size_t)(b * NKP + np)) * DM;
  *reinterpret_cast<ushort4*>(outp + c0) = o0;
  *reinterpret_cast<ushort4*>(outp + c1) = o1;
}

// ---------------- shared GEMM body: C[M,512] = A[M,512]*W[512,512]^T + bias ------------
template <int OMODE>
static __device__ __forceinline__ void gemm_body(const u16* __restrict__ A,
                                                 const u16* __restrict__ Bw,
                                                 const float* __restrict__ bias,
                                                 void* __restrict__ Cptr,
                                                 int nt, int mt,
                                                 u16* Al0, u16* Al1,
                                                 u16* Bl0, u16* Bl1) {
  int wv = threadIdx.x >> 6, lane = threadIdx.x & 63;
  int lr = lane & 15, lg = lane >> 4;
  int wr = wv >> 1, wc = wv & 1;
  int row0 = mt * 128, col0 = nt * 128;

  auto stage = [&](int kk, int bi) {
    u16* Al = bi ? Al1 : Al0;
    u16* Bl = bi ? Bl1 : Bl0;
    #pragma unroll
    for (int i = 0; i < 4; i++) {
      int t = wv * 4 + i;                    // 0..15
      int rr = (t & 7) * 16 + (lane >> 2);
      int cc = lane & 3;
      if (t < 8) {
        gl_lds16(A + (size_t)(row0 + rr) * DM + kk + cc * 8, (char*)Al + t * 1024);
      } else {
        gl_lds16(Bw + (size_t)(col0 + rr) * DM + kk + cc * 8, (char*)Bl + (t - 8) * 1024);
      }
    }
  };

  f32x4 acc[4][4] = {};
  stage(0, 0);
  __syncthreads();
  for (int s = 0; s < 16; s++) {
    int bi = s & 1;
    if (s < 15) stage((s + 1) * 32, bi ^ 1);
    u16* Al = bi ? Al1 : Al0;
    u16* Bl = bi ? Bl1 : Bl0;
    bf16x8 am[4], bn[4];
    #pragma unroll
    for (int m = 0; m < 4; m++)
      am[m] = ld8(Al + (wr * 64 + m * 16 + lr) * 32 + lg * 8);
    #pragma unroll
    for (int n = 0; n < 4; n++)
      bn[n] = ld8(Bl + (wc * 64 + n * 16 + lr) * 32 + lg * 8);
    #pragma unroll
    for (int m = 0; m < 4; m++)
      #pragma unroll
      for (int n = 0; n < 4; n++)
        acc[m][n] = mfma16(am[m], bn[n], acc[m][n]);
    __syncthreads();
  }
  if (OMODE == 2) {
    #pragma unroll
    for (int n = 0; n < 4; n++) {
      int col = col0 + wc * 64 + n * 16 + lr;
      float bs = bias[col];
      #pragma unroll
      for (int m = 0; m < 4; m++) {
        int rbase = row0 + wr * 64 + m * 16 + lg * 4;
        int bb = rbase / NKP;
        int kr = rbase % NKP;          // kr&15 == lg*4
        ushort4 o4;
        o4.x = f2bf(acc[m][n][0] + bs);
        o4.y = f2bf(acc[m][n][1] + bs);
        o4.z = f2bf(acc[m][n][2] + bs);
        o4.w = f2bf(acc[m][n][3] + bs);
        size_t dst = (((size_t)bb * 13 + (kr >> 4)) * 512 + col) * 16 + (kr & 15);
        *reinterpret_cast<ushort4*>(&((u16*)Cptr)[dst]) = o4;
      }
    }
  } else {
    #pragma unroll
    for (int n = 0; n < 4; n++) {
      int col = col0 + wc * 64 + n * 16 + lr;
      float bs = bias[col];
      #pragma unroll
      for (int m = 0; m < 4; m++) {
        #pragma unroll
        for (int r = 0; r < 4; r++) {
          int row = row0 + wr * 64 + m * 16 + lg * 4 + r;
          float v = acc[m][n][r] + bs;
          if (OMODE == 0) {
            ((u16*)Cptr)[(size_t)row * DM + col] = f2bf(v);
          } else {
            ((float*)Cptr)[(size_t)row * DM + col] = v;
          }
        }
      }
    }
  }
}

template <int OMODE>
__global__ __launch_bounds__(256) void gemm2_kernel(const u16* __restrict__ A,
                                                    const u16* __restrict__ Bw,
                                                    const float* __restrict__ bias,
                                                    void* __restrict__ Cptr) {
  __shared__ __align__(16) u16 Al[2][128 * 32];
  __shared__ __align__(16) u16 Bl[2][128 * 32];
  gemm_body<OMODE>(A, Bw, bias, Cptr, blockIdx.x, blockIdx.y,
                   &Al[0][0], &Al[1][0], &Bl[0][0], &Bl[1][0]);
}

// fused K-proj (OMODE 0) + V-proj (OMODE 2): blockIdx.z selects.
__global__ __launch_bounds__(256) void kvgemm_kernel(const u16* __restrict__ A,
                                                     const u16* __restrict__ Wk,
                                                     const float* __restrict__ bk,
                                                     void* __restrict__ Kout,
                                                     const u16* __restrict__ Wv,
                                                     const float* __restrict__ bv,
                                                     void* __restrict__ Vout) {
  __shared__ __align__(16) u16 Al[2][128 * 32];
  __shared__ __align__(16) u16 Bl[2][128 * 32];
  if (blockIdx.z == 0) {
    gemm_body<0>(A, Wk, bk, Kout, blockIdx.x, blockIdx.y,
                 &Al[0][0], &Al[1][0], &Bl[0][0], &Bl[1][0]);
  } else {
    gemm_body<2>(A, Wv, bv, Vout, blockIdx.x, blockIdx.y,
                 &Al[0][0], &Al[1][0], &Bl[0][0], &Bl[1][0]);
  }
}

// ---------------- fused attn: de-duplicated QK^T, LANE-ORDER score exchange ------------
// Round-16 fix over round 15: the s2 tile is stored in LANE ORDER — float
// offset (t*8+h)*256 + lane*4 — so every ds_write_b128/ds_read_b128 has
// contiguous 16B-per-lane addressing (zero bank conflicts; round 15's
// q-major layout lr*16+lg*4 had 64B/lane stride -> 4-way conflicts -> 13.3M
// conflict cycles). Writer and reader use the SAME lane->(q,k-slot) mapping,
// so the permutation is transparent to correctness.
__global__ __launch_bounds__(256) void attn_kernel(const u16* __restrict__ Q,
                                                   const u16* __restrict__ K,
                                                   const u16* __restrict__ VTt,
                                                   const float* __restrict__ tw,
                                                   u16* __restrict__ Oat) {
  __shared__ __align__(16) u16 Kl[2][16 * 512];   // 2 x 16KB, chunk-major
  __shared__ __align__(16) float s2[2 * 8 * 256]; // 16KB raw scores, lane-order tiles
  int i = blockIdx.x;
  int g8 = i & 7;            // XCD group == b%8
  int j = i >> 3;            // 0..199
  int qc = j % 25;
  int b = g8 + 8 * (j / 25);
  int tid = threadIdx.x, wv = tid >> 6, lane = tid & 63;
  int lr = lane & 15, lg = lane >> 4;
  int q0A = qc * 32;
  int q0B = (qc < 24) ? (q0A + 16) : q0A;   // tail duplicates tile A
  int g0 = wv * 2;           // this wave's raw-head pair AND output-head pair

  const u16* Kb = K + (size_t)b * NKP * DM;
  const u16* Vtb = VTt + (size_t)b * 13 * 8192;

  // wave-uniform mixing weights -> SGPRs (1/sqrt(64) folded)
  float w0[8], w1[8];
  #pragma unroll
  for (int h = 0; h < 8; h++) {
    w0[h] = sgpr_f(tw[(g0 + 0) * 8 + h] * 0.125f);
    w1[h] = sgpr_f(tw[(g0 + 1) * 8 + h] * 0.125f);
  }

  // Q fragments REGISTER-resident: only this wave's 2 raw heads x 2 tiles.
  bf16x8 qr[2][2][2];   // [tile][hh][half]
  #pragma unroll
  for (int t = 0; t < 2; t++) {
    const u16* Qb = Q + ((size_t)b * NQ + (t ? q0B : q0A)) * DM;
    #pragma unroll
    for (int hh = 0; hh < 2; hh++) {
      qr[t][hh][0] = ld8(Qb + (size_t)lr * DM + (g0 + hh) * 64 + lg * 8);
      qr[t][hh][1] = ld8(Qb + (size_t)lr * DM + (g0 + hh) * 64 + 32 + lg * 8);
    }
  }

  // chunk-major staging: slot s = g*64+lane -> (c = g*4 + lane>>4, r = lane&15)
  auto stageK = [&](int kt, int bi) {
    #pragma unroll
    for (int i2 = 0; i2 < 4; i2++) {
      int g = wv * 4 + i2;
      gl_lds16(Kb + (size_t)(kt * 16 + (lane & 15)) * DM + (g * 4 + (lane >> 4)) * 8,
               (char*)&Kl[bi][0] + g * 1024);
    }
  };
  stageK(0, 0);
  __syncthreads();

  f32x4 o[2][2][4] = {};      // [tile][g][j]
  float sumA0 = 0.f, sumA1 = 0.f, sumB0 = 0.f, sumB1 = 0.f;

  for (int kt = 0; kt < 13; kt++) {
    int bi = kt & 1;
    const u16* kbase = &Kl[bi][0] + lg * 128 + lr * 8;

    // ---- 1st half: QK^T for this wave's 2 raw heads, both tiles ----
    f32x4 sc[2][2];   // [tile][hh]
    #pragma unroll
    for (int hh = 0; hh < 2; hh++) {
      bf16x8 kf0 = ld8(kbase + (g0 + hh) * 1024);
      bf16x8 kf1 = ld8(kbase + (g0 + hh) * 1024 + 512);
      #pragma unroll
      for (int t = 0; t < 2; t++) {
        f32x4 tt = {0.f, 0.f, 0.f, 0.f};
        tt = mfma16(kf0, qr[t][hh][0], tt);
        tt = mfma16(kf1, qr[t][hh][1], tt);
        sc[t][hh] = tt;
      }
    }
    // write raw scores in LANE ORDER: float offset = tile_base + lane*4
    // (contiguous 16B per lane -> conflict-free)
    #pragma unroll
    for (int t = 0; t < 2; t++)
      #pragma unroll
      for (int hh = 0; hh < 2; hh++)
        *reinterpret_cast<f32x4*>(s2 + (t * 8 + g0 + hh) * 256 + lane * 4) =
            sc[t][hh];
    __syncthreads();   // scores visible to all waves

    // ---- 2nd half: stage next K + early V, then mix/exp/PV ----
    if (kt < 12) stageK(kt + 1, bi ^ 1);
    s16x4 vb[2][4];
    #pragma unroll
    for (int gi = 0; gi < 2; gi++) {
      #pragma unroll
      for (int j2 = 0; j2 < 4; j2++) {
        int d = (g0 + gi) * 64 + j2 * 16 + lr;
        vb[gi][j2] = *reinterpret_cast<const s16x4*>(
            Vtb + (size_t)kt * 8192 + d * 16 + lg * 4);
      }
    }

    bool masked = (kt == 12) && (lg != 0);   // k >= 196
    s16x4 pa[2][2];
    #pragma unroll
    for (int t = 0; t < 2; t++) {
      f32x4 sa = {0.f, 0.f, 0.f, 0.f};
      f32x4 sb = {0.f, 0.f, 0.f, 0.f};
      #pragma unroll
      for (int h = 0; h < 8; h++) {
        f32x4 scv = *reinterpret_cast<const f32x4*>(
            s2 + (t * 8 + h) * 256 + lane * 4);
        sa += scv * w0[h];
        sb += scv * w1[h];
      }
      float e0 = masked ? 0.f : __expf(sa[0]);
      float e1 = masked ? 0.f : __expf(sa[1]);
      float e2 = masked ? 0.f : __expf(sa[2]);
      float e3 = masked ? 0.f : __expf(sa[3]);
      float f0 = masked ? 0.f : __expf(sb[0]);
      float f1 = masked ? 0.f : __expf(sb[1]);
      float f2 = masked ? 0.f : __expf(sb[2]);
      float f3 = masked ? 0.f : __expf(sb[3]);
      if (t == 0) {
        sumA0 += (e0 + e1) + (e2 + e3);
        sumA1 += (f0 + f1) + (f2 + f3);
      } else {
        sumB0 += (e0 + e1) + (e2 + e3);
        sumB1 += (f0 + f1) + (f2 + f3);
      }
      union { __bf16 e[4]; s16x4 sv; } pk;
      pk.e[0] = (__bf16)e0; pk.e[1] = (__bf16)e1;
      pk.e[2] = (__bf16)e2; pk.e[3] = (__bf16)e3;
      pa[t][0] = pk.sv;
      pk.e[0] = (__bf16)f0; pk.e[1] = (__bf16)f1;
      pk.e[2] = (__bf16)f2; pk.e[3] = (__bf16)f3;
      pa[t][1] = pk.sv;
    }

    // PV: both tiles share vb
    __builtin_amdgcn_s_setprio(1);
    #pragma unroll
    for (int t = 0; t < 2; t++) {
      #pragma unroll
      for (int gi = 0; gi < 2; gi++) {
        #pragma unroll
        for (int j2 = 0; j2 < 4; j2++)
          o[t][gi][j2] = mfma16k16(pa[t][gi], vb[gi][j2], o[t][gi][j2]);
      }
    }
    __builtin_amdgcn_s_setprio(0);
    __syncthreads();   // stage(kt+1) drained; s2/Kl[bi] reusable next phase
  }

  // complete row sums (k split across lane groups 16 apart)
  sumA0 += __shfl_xor(sumA0, 16); sumA0 += __shfl_xor(sumA0, 32);
  sumA1 += __shfl_xor(sumA1, 16); sumA1 += __shfl_xor(sumA1, 32);
  sumB0 += __shfl_xor(sumB0, 16); sumB0 += __shfl_xor(sumB0, 32);
  sumB1 += __shfl_xor(sumB1, 16); sumB1 += __shfl_xor(sumB1, 32);
  float ivA0 = 1.0f / sumA0, ivA1 = 1.0f / sumA1;
  float ivB0 = 1.0f / sumB0, ivB1 = 1.0f / sumB1;
  #pragma unroll
  for (int t = 0; t < 2; t++) {
    if (t == 1 && qc == 24) break;   // tail: tile B is a duplicate
    int q0 = t ? q0B : q0A;
    #pragma unroll
    for (int gi = 0; gi < 2; gi++) {
      int g = g0 + gi;
      float ivsrc = t ? (gi ? ivB1 : ivB0) : (gi ? ivA1 : ivA0);
      #pragma unroll
      for (int r = 0; r < 4; r++) {
        int q = lg * 4 + r;
        float iv = __shfl(ivsrc, q);   // sum lives at lane lr == q
        #pragma unroll
        for (int j2 = 0; j2 < 4; j2++) {
          Oat[((size_t)(b * NQ + q0 + q)) * DM + g * 64 + j2 * 16 + lr] =
              f2bf(o[t][gi][j2][r] * iv);
        }
      }
    }
  }
}

// ---------------- launch ----------------
extern "C" void kernel_launch(void* const* d_in, const int* in_sizes, int n_in,
                              void* d_out, int out_size, void* d_ws, size_t ws_size,
                              hipStream_t stream) {
  const float* queries = (const float*)d_in[0];
  const float* Wq = (const float*)d_in[3];
  const float* bq = (const float*)d_in[4];
  const float* Wk = (const float*)d_in[5];
  const float* bk = (const float*)d_in[6];
  const float* Wv = (const float*)d_in[7];
  const float* bv = (const float*)d_in[8];
  const float* Wo = (const float*)d_in[9];
  const float* bo = (const float*)d_in[10];
  const float* sr_w = (const float*)d_in[11];
  const float* sr_b = (const float*)d_in[12];
  const float* ln_w = (const float*)d_in[13];
  const float* ln_b = (const float*)d_in[14];
  const float* tw = (const float*)d_in[15];

  char* ws = (char*)d_ws;
  u16* wq_bf = (u16*)(ws + 0);          // 512KB
  u16* wk_bf = (u16*)(ws + 524288);
  u16* wv_bf = (u16*)(ws + 1048576);
  u16* wo_bf = (u16*)(ws + 1572864);
  u16* xln   = (u16*)(ws + 2097152);    // 64*208*512*2 = 13,631,488
  u16* Kbuf  = (u16*)(ws + 15728640);   // 13,631,488
  u16* VTt   = (u16*)(ws + 29360128);   // 64*13*512*16*2 = 13,631,488
  u16* Qbuf  = (u16*)(ws + 42991616);   // 64*784*512*2 = 51,380,224
  u16* qbf   = (u16*)(ws + 94371840);   // 51,380,224 -> end 145,752,064
  u16* Oat   = qbf;                     // qbf dead after Q-proj; attn reuses it
  if (ws_size < 145752064u) return;     // fail loudly (output stays poisoned)

  const int NW = 262144;  // 512*512
  cvt_kernel<<<256, 256, 0, stream>>>(Wq, wq_bf, NW);
  cvt_kernel<<<256, 256, 0, stream>>>(Wk, wk_bf, NW);
  cvt_kernel<<<256, 256, 0, stream>>>(Wv, wv_bf, NW);
  cvt_kernel<<<256, 256, 0, stream>>>(Wo, wo_bf, NW);

  // fused queries cvt + LN: 64*784 + 64*12 waves
  cvtln_kernel<<<(NB * NQ + NB * 12 + 3) / 4, 256, 0, stream>>>(
      queries, sr_w, sr_b, ln_w, ln_b, qbf, xln);

  // Q = qbf @ Wq^T + bq   M = 50176
  gemm2_kernel<0><<<dim3(4, 392), 256, 0, stream>>>(qbf, wq_bf, bq, Qbuf);
  // K-proj + V-proj fused (z=0: K [row][col] bf16; z=1: V tiled)
  kvgemm_kernel<<<dim3(4, 104, 2), 256, 0, stream>>>(xln, wk_bf, bk, Kbuf,
                                                     wv_bf, bv, VTt);

  attn_kernel<<<dim3(1600), 256, 0, stream>>>(Qbuf, Kbuf, VTt, tw, Oat);

  // out = Oat @ Wo^T + bo  (fp32 out)
  gemm2_kernel<1><<<dim3(4, 392), 256, 0, stream>>>(Oat, wo_bf, bo, d_out);
}

// Round 17
// 303.732 us; speedup vs baseline: 1.0817x; 1.0457x over previous
//
#include <hip/hip_runtime.h>
#include <stdint.h>

typedef unsigned short u16;
typedef unsigned int   u32;
typedef __attribute__((ext_vector_type(8))) __bf16 bf16x8;
typedef __attribute__((ext_vector_type(4))) float  f32x4;
typedef __attribute__((ext_vector_type(4))) short  s16x4;

#define NB  64
#define NQ  784
#define NK  196
#define NKP 208      // nk padded to 13*16
#define DM  512

static __device__ inline u16 f2bf(float f) {
  u32 u = __float_as_uint(f);
  u32 r = (u + 0x7fffu + ((u >> 16) & 1u)) >> 16;
  return (u16)r;
}

static __device__ inline bf16x8 ld8(const u16* p) {
  return *reinterpret_cast<const bf16x8*>(p);
}
static __device__ inline f32x4 mfma16(bf16x8 a, bf16x8 b, f32x4 c) {
  return __builtin_amdgcn_mfma_f32_16x16x32_bf16(a, b, c, 0, 0, 0);
}
// K=16 bf16 MFMA (4 bf16 per lane per operand)
static __device__ inline f32x4 mfma16k16(s16x4 a, s16x4 b, f32x4 c) {
#if __has_builtin(__builtin_amdgcn_mfma_f32_16x16x16bf16_1k)
  return __builtin_amdgcn_mfma_f32_16x16x16bf16_1k(a, b, c, 0, 0, 0);
#elif __has_builtin(__builtin_amdgcn_mfma_f32_16x16x16_bf16)
  typedef __attribute__((ext_vector_type(4))) __bf16 bf16x4_t;
  union { s16x4 s; bf16x4_t b; } ua, ub;
  ua.s = a; ub.s = b;
  return __builtin_amdgcn_mfma_f32_16x16x16_bf16(ua.b, ub.b, c, 0, 0, 0);
#else
  asm volatile("v_mfma_f32_16x16x16_bf16 %0, %1, %2, %0\n\ts_nop 7\n\ts_nop 7"
               : "+v"(c) : "v"(a), "v"(b));
  return c;
#endif
}

// wave-uniform float -> SGPR
static __device__ inline float sgpr_f(float x) {
  return __uint_as_float(__builtin_amdgcn_readfirstlane(__float_as_uint(x)));
}

// async global -> LDS, 16B per lane; LDS dest must be wave-uniform base
static __device__ inline void gl_lds16(const void* g, void* l) {
  __builtin_amdgcn_global_load_lds(
      (const __attribute__((address_space(1))) void*)g,
      (__attribute__((address_space(3))) void*)l, 16, 0, 0);
}

// ---------------- fp32 -> bf16 conversion (weights) ----------------
__global__ __launch_bounds__(256) void cvt_kernel(const float* __restrict__ in,
                                                  u16* __restrict__ out, int n) {
  int i = (blockIdx.x * 256 + threadIdx.x) * 4;
  if (i + 3 < n) {
    float4 f = *reinterpret_cast<const float4*>(in + i);
    ushort4 o;
    o.x = f2bf(f.x); o.y = f2bf(f.y); o.z = f2bf(f.z); o.w = f2bf(f.w);
    *reinterpret_cast<ushort4*>(out + i) = o;
  }
}

// ---------------- fused queries cvt (fp32->bf16) + spatial-reduce LayerNorm ------------
__global__ __launch_bounds__(256) void cvtln_kernel(const float* __restrict__ q,
                                                    const float* __restrict__ sr_w,
                                                    const float* __restrict__ sr_b,
                                                    const float* __restrict__ ln_w,
                                                    const float* __restrict__ ln_b,
                                                    u16* __restrict__ qbf,
                                                    u16* __restrict__ xln) {
  int w = blockIdx.x * 4 + (threadIdx.x >> 6);
  int lane = threadIdx.x & 63;
  if (w >= NB * NQ) {
    int w2 = w - NB * NQ;
    if (w2 < NB * 12) {
      int b = w2 / 12, pr = w2 % 12;
      u16* outp = xln + ((size_t)(b * NKP + NK + pr)) * DM;
      *reinterpret_cast<uint4*>(outp + lane * 8) = make_uint4(0u, 0u, 0u, 0u);
    }
    return;
  }
  int b = w / NQ, n = w % NQ;
  const float* row = q + ((size_t)w) * DM;
  int c0 = lane * 4, c1 = 256 + lane * 4;
  float4 x0 = *reinterpret_cast<const float4*>(row + c0);
  float4 x1 = *reinterpret_cast<const float4*>(row + c1);
  u16* qp = qbf + (size_t)w * DM;
  ushort4 q0, q1;
  q0.x = f2bf(x0.x); q0.y = f2bf(x0.y); q0.z = f2bf(x0.z); q0.w = f2bf(x0.w);
  q1.x = f2bf(x1.x); q1.y = f2bf(x1.y); q1.z = f2bf(x1.z); q1.w = f2bf(x1.w);
  *reinterpret_cast<ushort4*>(qp + c0) = q0;
  *reinterpret_cast<ushort4*>(qp + c1) = q1;
  int y = n / 28, x = n % 28;
  if ((y & 1) | (x & 1)) return;
  int np = (y >> 1) * 14 + (x >> 1);
  float4 w0 = *reinterpret_cast<const float4*>(sr_w + c0);
  float4 w1 = *reinterpret_cast<const float4*>(sr_w + c1);
  float4 s0 = *reinterpret_cast<const float4*>(sr_b + c0);
  float4 s1 = *reinterpret_cast<const float4*>(sr_b + c1);
  float yv[8];
  yv[0] = x0.x * w0.x + s0.x; yv[1] = x0.y * w0.y + s0.y;
  yv[2] = x0.z * w0.z + s0.z; yv[3] = x0.w * w0.w + s0.w;
  yv[4] = x1.x * w1.x + s1.x; yv[5] = x1.y * w1.y + s1.y;
  yv[6] = x1.z * w1.z + s1.z; yv[7] = x1.w * w1.w + s1.w;
  float s = 0.f, ss = 0.f;
  #pragma unroll
  for (int i = 0; i < 8; i++) { s += yv[i]; ss += yv[i] * yv[i]; }
  #pragma unroll
  for (int off = 1; off < 64; off <<= 1) {
    s += __shfl_xor(s, off); ss += __shfl_xor(ss, off);
  }
  float mu = s * (1.f / 512.f);
  float var = ss * (1.f / 512.f) - mu * mu;
  float rs = rsqrtf(var + 1e-5f);
  float4 lw0 = *reinterpret_cast<const float4*>(ln_w + c0);
  float4 lw1 = *reinterpret_cast<const float4*>(ln_w + c1);
  float4 lb0 = *reinterpret_cast<const float4*>(ln_b + c0);
  float4 lb1 = *reinterpret_cast<const float4*>(ln_b + c1);
  ushort4 o0, o1;
  o0.x = f2bf((yv[0] - mu) * rs * lw0.x + lb0.x);
  o0.y = f2bf((yv[1] - mu) * rs * lw0.y + lb0.y);
  o0.z = f2bf((yv[2] - mu) * rs * lw0.z + lb0.z);
  o0.w = f2bf((yv[3] - mu) * rs * lw0.w + lb0.w);
  o1.x = f2bf((yv[4] - mu) * rs * lw1.x + lb1.x);
  o1.y = f2bf((yv[5] - mu) * rs * lw1.y + lb1.y);
  o1.z = f2bf((yv[6] - mu) * rs * lw1.z + lb1.z);
  o1.w = f2bf((yv[7] - mu) * rs * lw1.w + lb1.w);
  u16* outp = xln + ((size_t)(b * NKP + np)) * DM;
  *reinterpret_cast<ushort4*>(outp + c0) = o0;
  *reinterpret_cast<ushort4*>(outp + c1) = o1;
}

// ---------------- shared GEMM body: C[M,512] = A[M,512]*W[512,512]^T + bias ------------
template <int OMODE>
static __device__ __forceinline__ void gemm_body(const u16* __restrict__ A,
                                                 const u16* __restrict__ Bw,
                                                 const float* __restrict__ bias,
                                                 void* __restrict__ Cptr,
                                                 int nt, int mt,
                                                 u16* Al0, u16* Al1,
                                                 u16* Bl0, u16* Bl1) {
  int wv = threadIdx.x >> 6, lane = threadIdx.x & 63;
  int lr = lane & 15, lg = lane >> 4;
  int wr = wv >> 1, wc = wv & 1;
  int row0 = mt * 128, col0 = nt * 128;

  auto stage = [&](int kk, int bi) {
    u16* Al = bi ? Al1 : Al0;
    u16* Bl = bi ? Bl1 : Bl0;
    #pragma unroll
    for (int i = 0; i < 4; i++) {
      int t = wv * 4 + i;                    // 0..15
      int rr = (t & 7) * 16 + (lane >> 2);
      int cc = lane & 3;
      if (t < 8) {
        gl_lds16(A + (size_t)(row0 + rr) * DM + kk + cc * 8, (char*)Al + t * 1024);
      } else {
        gl_lds16(Bw + (size_t)(col0 + rr) * DM + kk + cc * 8, (char*)Bl + (t - 8) * 1024);
      }
    }
  };

  f32x4 acc[4][4] = {};
  stage(0, 0);
  __syncthreads();
  for (int s = 0; s < 16; s++) {
    int bi = s & 1;
    if (s < 15) stage((s + 1) * 32, bi ^ 1);
    u16* Al = bi ? Al1 : Al0;
    u16* Bl = bi ? Bl1 : Bl0;
    bf16x8 am[4], bn[4];
    #pragma unroll
    for (int m = 0; m < 4; m++)
      am[m] = ld8(Al + (wr * 64 + m * 16 + lr) * 32 + lg * 8);
    #pragma unroll
    for (int n = 0; n < 4; n++)
      bn[n] = ld8(Bl + (wc * 64 + n * 16 + lr) * 32 + lg * 8);
    #pragma unroll
    for (int m = 0; m < 4; m++)
      #pragma unroll
      for (int n = 0; n < 4; n++)
        acc[m][n] = mfma16(am[m], bn[n], acc[m][n]);
    __syncthreads();
  }
  if (OMODE == 2) {
    #pragma unroll
    for (int n = 0; n < 4; n++) {
      int col = col0 + wc * 64 + n * 16 + lr;
      float bs = bias[col];
      #pragma unroll
      for (int m = 0; m < 4; m++) {
        int rbase = row0 + wr * 64 + m * 16 + lg * 4;
        int bb = rbase / NKP;
        int kr = rbase % NKP;          // kr&15 == lg*4
        ushort4 o4;
        o4.x = f2bf(acc[m][n][0] + bs);
        o4.y = f2bf(acc[m][n][1] + bs);
        o4.z = f2bf(acc[m][n][2] + bs);
        o4.w = f2bf(acc[m][n][3] + bs);
        size_t dst = (((size_t)bb * 13 + (kr >> 4)) * 512 + col) * 16 + (kr & 15);
        *reinterpret_cast<ushort4*>(&((u16*)Cptr)[dst]) = o4;
      }
    }
  } else {
    #pragma unroll
    for (int n = 0; n < 4; n++) {
      int col = col0 + wc * 64 + n * 16 + lr;
      float bs = bias[col];
      #pragma unroll
      for (int m = 0; m < 4; m++) {
        #pragma unroll
        for (int r = 0; r < 4; r++) {
          int row = row0 + wr * 64 + m * 16 + lg * 4 + r;
          float v = acc[m][n][r] + bs;
          if (OMODE == 0) {
            ((u16*)Cptr)[(size_t)row * DM + col] = f2bf(v);
          } else {
            ((float*)Cptr)[(size_t)row * DM + col] = v;
          }
        }
      }
    }
  }
}

template <int OMODE>
__global__ __launch_bounds__(256) void gemm2_kernel(const u16* __restrict__ A,
                                                    const u16* __restrict__ Bw,
                                                    const float* __restrict__ bias,
                                                    void* __restrict__ Cptr) {
  __shared__ __align__(16) u16 Al[2][128 * 32];
  __shared__ __align__(16) u16 Bl[2][128 * 32];
  gemm_body<OMODE>(A, Bw, bias, Cptr, blockIdx.x, blockIdx.y,
                   &Al[0][0], &Al[1][0], &Bl[0][0], &Bl[1][0]);
}

// fused K-proj (OMODE 0) + V-proj (OMODE 2): blockIdx.z selects.
__global__ __launch_bounds__(256) void kvgemm_kernel(const u16* __restrict__ A,
                                                     const u16* __restrict__ Wk,
                                                     const float* __restrict__ bk,
                                                     void* __restrict__ Kout,
                                                     const u16* __restrict__ Wv,
                                                     const float* __restrict__ bv,
                                                     void* __restrict__ Vout) {
  __shared__ __align__(16) u16 Al[2][128 * 32];
  __shared__ __align__(16) u16 Bl[2][128 * 32];
  if (blockIdx.z == 0) {
    gemm_body<0>(A, Wk, bk, Kout, blockIdx.x, blockIdx.y,
                 &Al[0][0], &Al[1][0], &Bl[0][0], &Bl[1][0]);
  } else {
    gemm_body<2>(A, Wv, bv, Vout, blockIdx.x, blockIdx.y,
                 &Al[0][0], &Al[1][0], &Bl[0][0], &Bl[1][0]);
  }
}

// ---------------- fused attn: ONE-barrier score exchange (pipelined mix/PV) ------------
// grid 1600 XCD-clustered (id%8 == b%8), 4 waves, 32 q-rows per block.
// Round-17: r16's dedup QK^T (each wave only its 2 raw heads: 4 kf reads +
// 8 MFMA) but mix/softmax/PV runs ONE kt BEHIND, reading the previous
// iteration's scores from double-buffered s2 — the single end-of-phase
// barrier covers both K-stage drain AND score visibility (r16's 2nd barrier
// eliminated; that barrier cost more than dedup saved: 154 vs r14's 139).
// Race audit: s2[bi] written iter kt / read iter kt+1 / overwritten iter
// kt+2 — all barrier-separated. Lane-order s2 tiles (conflict-free).
__global__ __launch_bounds__(256) void attn_kernel(const u16* __restrict__ Q,
                                                   const u16* __restrict__ K,
                                                   const u16* __restrict__ VTt,
                                                   const float* __restrict__ tw,
                                                   u16* __restrict__ Oat) {
  __shared__ __align__(16) u16 Kl[2][16 * 512];   // 2 x 16KB, chunk-major
  __shared__ __align__(16) float s2[2][16 * 256]; // 2 x 16KB, lane-order tiles
  int i = blockIdx.x;
  int g8 = i & 7;            // XCD group == b%8
  int j = i >> 3;            // 0..199
  int qc = j % 25;
  int b = g8 + 8 * (j / 25);
  int tid = threadIdx.x, wv = tid >> 6, lane = tid & 63;
  int lr = lane & 15, lg = lane >> 4;
  int q0A = qc * 32;
  int q0B = (qc < 24) ? (q0A + 16) : q0A;   // tail duplicates tile A
  int g0 = wv * 2;           // this wave's raw-head pair AND output-head pair

  const u16* Kb = K + (size_t)b * NKP * DM;
  const u16* Vtb = VTt + (size_t)b * 13 * 8192;

  // wave-uniform mixing weights -> SGPRs (1/sqrt(64) folded)
  float w0[8], w1[8];
  #pragma unroll
  for (int h = 0; h < 8; h++) {
    w0[h] = sgpr_f(tw[(g0 + 0) * 8 + h] * 0.125f);
    w1[h] = sgpr_f(tw[(g0 + 1) * 8 + h] * 0.125f);
  }

  // Q fragments REGISTER-resident: only this wave's 2 raw heads x 2 tiles.
  bf16x8 qr[2][2][2];   // [tile][hh][half]
  #pragma unroll
  for (int t = 0; t < 2; t++) {
    const u16* Qb = Q + ((size_t)b * NQ + (t ? q0B : q0A)) * DM;
    #pragma unroll
    for (int hh = 0; hh < 2; hh++) {
      qr[t][hh][0] = ld8(Qb + (size_t)lr * DM + (g0 + hh) * 64 + lg * 8);
      qr[t][hh][1] = ld8(Qb + (size_t)lr * DM + (g0 + hh) * 64 + 32 + lg * 8);
    }
  }

  // chunk-major staging: slot s = g*64+lane -> (c = g*4 + lane>>4, r = lane&15)
  auto stageK = [&](int kt, int bi) {
    #pragma unroll
    for (int i2 = 0; i2 < 4; i2++) {
      int g = wv * 4 + i2;
      gl_lds16(Kb + (size_t)(kt * 16 + (lane & 15)) * DM + (g * 4 + (lane >> 4)) * 8,
               (char*)&Kl[bi][0] + g * 1024);
    }
  };
  stageK(0, 0);
  __syncthreads();

  f32x4 o[2][2][4] = {};      // [tile][g][j]
  float sumA0 = 0.f, sumA1 = 0.f, sumB0 = 0.f, sumB1 = 0.f;
  s16x4 vb[2][4];

  // mix + exp + PV for k-tile ktm, scores in s2[sbi]
  auto mixpv = [&](int ktm, int sbi) {
    bool masked = (ktm == 12) && (lg != 0);   // k >= 196
    s16x4 pa[2][2];
    #pragma unroll
    for (int t = 0; t < 2; t++) {
      f32x4 sa = {0.f, 0.f, 0.f, 0.f};
      f32x4 sb = {0.f, 0.f, 0.f, 0.f};
      #pragma unroll
      for (int h = 0; h < 8; h++) {
        f32x4 scv = *reinterpret_cast<const f32x4*>(
            &s2[sbi][0] + (t * 8 + h) * 256 + lane * 4);
        sa += scv * w0[h];
        sb += scv * w1[h];
      }
      float e0 = masked ? 0.f : __expf(sa[0]);
      float e1 = masked ? 0.f : __expf(sa[1]);
      float e2 = masked ? 0.f : __expf(sa[2]);
      float e3 = masked ? 0.f : __expf(sa[3]);
      float f0 = masked ? 0.f : __expf(sb[0]);
      float f1 = masked ? 0.f : __expf(sb[1]);
      float f2 = masked ? 0.f : __expf(sb[2]);
      float f3 = masked ? 0.f : __expf(sb[3]);
      if (t == 0) {
        sumA0 += (e0 + e1) + (e2 + e3);
        sumA1 += (f0 + f1) + (f2 + f3);
      } else {
        sumB0 += (e0 + e1) + (e2 + e3);
        sumB1 += (f0 + f1) + (f2 + f3);
      }
      union { __bf16 e[4]; s16x4 sv; } pk;
      pk.e[0] = (__bf16)e0; pk.e[1] = (__bf16)e1;
      pk.e[2] = (__bf16)e2; pk.e[3] = (__bf16)e3;
      pa[t][0] = pk.sv;
      pk.e[0] = (__bf16)f0; pk.e[1] = (__bf16)f1;
      pk.e[2] = (__bf16)f2; pk.e[3] = (__bf16)f3;
      pa[t][1] = pk.sv;
    }
    __builtin_amdgcn_s_setprio(1);
    #pragma unroll
    for (int t = 0; t < 2; t++) {
      #pragma unroll
      for (int gi = 0; gi < 2; gi++) {
        #pragma unroll
        for (int j2 = 0; j2 < 4; j2++)
          o[t][gi][j2] = mfma16k16(pa[t][gi], vb[gi][j2], o[t][gi][j2]);
      }
    }
    __builtin_amdgcn_s_setprio(0);
  };

  for (int kt = 0; kt < 13; kt++) {
    int bi = kt & 1;

    // EARLY V for the pipelined mix/PV of kt-1 (latency hidden under QK^T)
    if (kt > 0) {
      #pragma unroll
      for (int gi = 0; gi < 2; gi++) {
        #pragma unroll
        for (int j2 = 0; j2 < 4; j2++) {
          int d = (g0 + gi) * 64 + j2 * 16 + lr;
          vb[gi][j2] = *reinterpret_cast<const s16x4*>(
              Vtb + (size_t)(kt - 1) * 8192 + d * 16 + lg * 4);
        }
      }
    }

    // QK^T(kt) for this wave's 2 raw heads, both tiles; write s2[bi]
    const u16* kbase = &Kl[bi][0] + lg * 128 + lr * 8;
    __builtin_amdgcn_s_setprio(1);
    #pragma unroll
    for (int hh = 0; hh < 2; hh++) {
      bf16x8 kf0 = ld8(kbase + (g0 + hh) * 1024);
      bf16x8 kf1 = ld8(kbase + (g0 + hh) * 1024 + 512);
      #pragma unroll
      for (int t = 0; t < 2; t++) {
        f32x4 tt = {0.f, 0.f, 0.f, 0.f};
        tt = mfma16(kf0, qr[t][hh][0], tt);
        tt = mfma16(kf1, qr[t][hh][1], tt);
        *reinterpret_cast<f32x4*>(&s2[bi][0] + (t * 8 + g0 + hh) * 256 + lane * 4) = tt;
      }
    }
    __builtin_amdgcn_s_setprio(0);

    // stage K(kt+1) into the buffer QK^T(kt+1) will read
    if (kt < 12) stageK(kt + 1, bi ^ 1);

    // pipelined mix/exp/PV for kt-1 (scores from s2[bi^1], visible since
    // the barrier at the end of iteration kt-1)
    if (kt > 0) mixpv(kt - 1, bi ^ 1);

    __syncthreads();   // drains stage(kt+1); s2[bi] visible for iter kt+1
  }
  // epilogue: mix/PV for kt=12 (scores in s2[12&1=0], visible after last barrier)
  {
    #pragma unroll
    for (int gi = 0; gi < 2; gi++) {
      #pragma unroll
      for (int j2 = 0; j2 < 4; j2++) {
        int d = (g0 + gi) * 64 + j2 * 16 + lr;
        vb[gi][j2] = *reinterpret_cast<const s16x4*>(
            Vtb + (size_t)12 * 8192 + d * 16 + lg * 4);
      }
    }
    mixpv(12, 0);
  }

  // complete row sums (k split across lane groups 16 apart)
  sumA0 += __shfl_xor(sumA0, 16); sumA0 += __shfl_xor(sumA0, 32);
  sumA1 += __shfl_xor(sumA1, 16); sumA1 += __shfl_xor(sumA1, 32);
  sumB0 += __shfl_xor(sumB0, 16); sumB0 += __shfl_xor(sumB0, 32);
  sumB1 += __shfl_xor(sumB1, 16); sumB1 += __shfl_xor(sumB1, 32);
  float ivA0 = 1.0f / sumA0, ivA1 = 1.0f / sumA1;
  float ivB0 = 1.0f / sumB0, ivB1 = 1.0f / sumB1;
  #pragma unroll
  for (int t = 0; t < 2; t++) {
    if (t == 1 && qc == 24) break;   // tail: tile B is a duplicate
    int q0 = t ? q0B : q0A;
    #pragma unroll
    for (int gi = 0; gi < 2; gi++) {
      int g = g0 + gi;
      float ivsrc = t ? (gi ? ivB1 : ivB0) : (gi ? ivA1 : ivA0);
      #pragma unroll
      for (int r = 0; r < 4; r++) {
        int q = lg * 4 + r;
        float iv = __shfl(ivsrc, q);   // sum lives at lane lr == q
        #pragma unroll
        for (int j2 = 0; j2 < 4; j2++) {
          Oat[((size_t)(b * NQ + q0 + q)) * DM + g * 64 + j2 * 16 + lr] =
              f2bf(o[t][gi][j2][r] * iv);
        }
      }
    }
  }
}

// ---------------- launch ----------------
extern "C" void kernel_launch(void* const* d_in, const int* in_sizes, int n_in,
                              void* d_out, int out_size, void* d_ws, size_t ws_size,
                              hipStream_t stream) {
  const float* queries = (const float*)d_in[0];
  const float* Wq = (const float*)d_in[3];
  const float* bq = (const float*)d_in[4];
  const float* Wk = (const float*)d_in[5];
  const float* bk = (const float*)d_in[6];
  const float* Wv = (const float*)d_in[7];
  const float* bv = (const float*)d_in[8];
  const float* Wo = (const float*)d_in[9];
  const float* bo = (const float*)d_in[10];
  const float* sr_w = (const float*)d_in[11];
  const float* sr_b = (const float*)d_in[12];
  const float* ln_w = (const float*)d_in[13];
  const float* ln_b = (const float*)d_in[14];
  const float* tw = (const float*)d_in[15];

  char* ws = (char*)d_ws;
  u16* wq_bf = (u16*)(ws + 0);          // 512KB
  u16* wk_bf = (u16*)(ws + 524288);
  u16* wv_bf = (u16*)(ws + 1048576);
  u16* wo_bf = (u16*)(ws + 1572864);
  u16* xln   = (u16*)(ws + 2097152);    // 64*208*512*2 = 13,631,488
  u16* Kbuf  = (u16*)(ws + 15728640);   // 13,631,488
  u16* VTt   = (u16*)(ws + 29360128);   // 64*13*512*16*2 = 13,631,488
  u16* Qbuf  = (u16*)(ws + 42991616);   // 64*784*512*2 = 51,380,224
  u16* qbf   = (u16*)(ws + 94371840);   // 51,380,224 -> end 145,752,064
  u16* Oat   = qbf;                     // qbf dead after Q-proj; attn reuses it
  if (ws_size < 145752064u) return;     // fail loudly (output stays poisoned)

  const int NW = 262144;  // 512*512
  cvt_kernel<<<256, 256, 0, stream>>>(Wq, wq_bf, NW);
  cvt_kernel<<<256, 256, 0, stream>>>(Wk, wk_bf, NW);
  cvt_kernel<<<256, 256, 0, stream>>>(Wv, wv_bf, NW);
  cvt_kernel<<<256, 256, 0, stream>>>(Wo, wo_bf, NW);

  // fused queries cvt + LN: 64*784 + 64*12 waves
  cvtln_kernel<<<(NB * NQ + NB * 12 + 3) / 4, 256, 0, stream>>>(
      queries, sr_w, sr_b, ln_w, ln_b, qbf, xln);

  // Q = qbf @ Wq^T + bq   M = 50176
  gemm2_kernel<0><<<dim3(4, 392), 256, 0, stream>>>(qbf, wq_bf, bq, Qbuf);
  // K-proj + V-proj fused (z=0: K [row][col] bf16; z=1: V tiled)
  kvgemm_kernel<<<dim3(4, 104, 2), 256, 0, stream>>>(xln, wk_bf, bk, Kbuf,
                                                     wv_bf, bv, VTt);

  attn_kernel<<<dim3(1600), 256, 0, stream>>>(Qbuf, Kbuf, VTt, tw, Oat);

  // out = Oat @ Wo^T + bo  (fp32 out)
  gemm2_kernel<1><<<dim3(4, 392), 256, 0, stream>>>(Oat, wo_bf, bo, d_out);
}

// Round 18
// 297.590 us; speedup vs baseline: 1.1041x; 1.0206x over previous
//
#include <hip/hip_runtime.h>
#include <stdint.h>

typedef unsigned short u16;
typedef unsigned int   u32;
typedef __attribute__((ext_vector_type(8))) __bf16 bf16x8;
typedef __attribute__((ext_vector_type(4))) float  f32x4;
typedef __attribute__((ext_vector_type(4))) short  s16x4;

#define NB  64
#define NQ  784
#define NK  196
#define NKP 208      // nk padded to 13*16
#define DM  512

static __device__ inline u16 f2bf(float f) {
  u32 u = __float_as_uint(f);
  u32 r = (u + 0x7fffu + ((u >> 16) & 1u)) >> 16;
  return (u16)r;
}

static __device__ inline bf16x8 ld8(const u16* p) {
  return *reinterpret_cast<const bf16x8*>(p);
}
static __device__ inline f32x4 mfma16(bf16x8 a, bf16x8 b, f32x4 c) {
  return __builtin_amdgcn_mfma_f32_16x16x32_bf16(a, b, c, 0, 0, 0);
}
// K=16 bf16 MFMA (4 bf16 per lane per operand)
static __device__ inline f32x4 mfma16k16(s16x4 a, s16x4 b, f32x4 c) {
#if __has_builtin(__builtin_amdgcn_mfma_f32_16x16x16bf16_1k)
  return __builtin_amdgcn_mfma_f32_16x16x16bf16_1k(a, b, c, 0, 0, 0);
#elif __has_builtin(__builtin_amdgcn_mfma_f32_16x16x16_bf16)
  typedef __attribute__((ext_vector_type(4))) __bf16 bf16x4_t;
  union { s16x4 s; bf16x4_t b; } ua, ub;
  ua.s = a; ub.s = b;
  return __builtin_amdgcn_mfma_f32_16x16x16_bf16(ua.b, ub.b, c, 0, 0, 0);
#else
  asm volatile("v_mfma_f32_16x16x16_bf16 %0, %1, %2, %0\n\ts_nop 7\n\ts_nop 7"
               : "+v"(c) : "v"(a), "v"(b));
  return c;
#endif
}

// wave-uniform float -> SGPR
static __device__ inline float sgpr_f(float x) {
  return __uint_as_float(__builtin_amdgcn_readfirstlane(__float_as_uint(x)));
}

// async global -> LDS, 16B per lane; LDS dest must be wave-uniform base
static __device__ inline void gl_lds16(const void* g, void* l) {
  __builtin_amdgcn_global_load_lds(
      (const __attribute__((address_space(1))) void*)g,
      (__attribute__((address_space(3))) void*)l, 16, 0, 0);
}

// ---------------- fused fp32 -> bf16 conversion of the 4 weight matrices ---------------
__global__ __launch_bounds__(256) void cvt4_kernel(const float* __restrict__ Wq,
                                                   const float* __restrict__ Wk,
                                                   const float* __restrict__ Wv,
                                                   const float* __restrict__ Wo,
                                                   u16* __restrict__ oq,
                                                   u16* __restrict__ ok,
                                                   u16* __restrict__ ov,
                                                   u16* __restrict__ oo) {
  int sel = blockIdx.x >> 8;
  int blk = blockIdx.x & 255;
  const float* in = (sel == 0) ? Wq : (sel == 1) ? Wk : (sel == 2) ? Wv : Wo;
  u16* out = (sel == 0) ? oq : (sel == 1) ? ok : (sel == 2) ? ov : oo;
  int i = (blk * 256 + threadIdx.x) * 4;
  float4 f = *reinterpret_cast<const float4*>(in + i);
  ushort4 o;
  o.x = f2bf(f.x); o.y = f2bf(f.y); o.z = f2bf(f.z); o.w = f2bf(f.w);
  *reinterpret_cast<ushort4*>(out + i) = o;
}

// ---------------- fused queries cvt (fp32->bf16) + spatial-reduce LayerNorm ------------
__global__ __launch_bounds__(256) void cvtln_kernel(const float* __restrict__ q,
                                                    const float* __restrict__ sr_w,
                                                    const float* __restrict__ sr_b,
                                                    const float* __restrict__ ln_w,
                                                    const float* __restrict__ ln_b,
                                                    u16* __restrict__ qbf,
                                                    u16* __restrict__ xln) {
  int w = blockIdx.x * 4 + (threadIdx.x >> 6);
  int lane = threadIdx.x & 63;
  if (w >= NB * NQ) {
    int w2 = w - NB * NQ;
    if (w2 < NB * 12) {
      int b = w2 / 12, pr = w2 % 12;
      u16* outp = xln + ((size_t)(b * NKP + NK + pr)) * DM;
      *reinterpret_cast<uint4*>(outp + lane * 8) = make_uint4(0u, 0u, 0u, 0u);
    }
    return;
  }
  int b = w / NQ, n = w % NQ;
  const float* row = q + ((size_t)w) * DM;
  int c0 = lane * 4, c1 = 256 + lane * 4;
  float4 x0 = *reinterpret_cast<const float4*>(row + c0);
  float4 x1 = *reinterpret_cast<const float4*>(row + c1);
  u16* qp = qbf + (size_t)w * DM;
  ushort4 q0, q1;
  q0.x = f2bf(x0.x); q0.y = f2bf(x0.y); q0.z = f2bf(x0.z); q0.w = f2bf(x0.w);
  q1.x = f2bf(x1.x); q1.y = f2bf(x1.y); q1.z = f2bf(x1.z); q1.w = f2bf(x1.w);
  *reinterpret_cast<ushort4*>(qp + c0) = q0;
  *reinterpret_cast<ushort4*>(qp + c1) = q1;
  int y = n / 28, x = n % 28;
  if ((y & 1) | (x & 1)) return;
  int np = (y >> 1) * 14 + (x >> 1);
  float4 w0 = *reinterpret_cast<const float4*>(sr_w + c0);
  float4 w1 = *reinterpret_cast<const float4*>(sr_w + c1);
  float4 s0 = *reinterpret_cast<const float4*>(sr_b + c0);
  float4 s1 = *reinterpret_cast<const float4*>(sr_b + c1);
  float yv[8];
  yv[0] = x0.x * w0.x + s0.x; yv[1] = x0.y * w0.y + s0.y;
  yv[2] = x0.z * w0.z + s0.z; yv[3] = x0.w * w0.w + s0.w;
  yv[4] = x1.x * w1.x + s1.x; yv[5] = x1.y * w1.y + s1.y;
  yv[6] = x1.z * w1.z + s1.z; yv[7] = x1.w * w1.w + s1.w;
  float s = 0.f, ss = 0.f;
  #pragma unroll
  for (int i = 0; i < 8; i++) { s += yv[i]; ss += yv[i] * yv[i]; }
  #pragma unroll
  for (int off = 1; off < 64; off <<= 1) {
    s += __shfl_xor(s, off); ss += __shfl_xor(ss, off);
  }
  float mu = s * (1.f / 512.f);
  float var = ss * (1.f / 512.f) - mu * mu;
  float rs = rsqrtf(var + 1e-5f);
  float4 lw0 = *reinterpret_cast<const float4*>(ln_w + c0);
  float4 lw1 = *reinterpret_cast<const float4*>(ln_w + c1);
  float4 lb0 = *reinterpret_cast<const float4*>(ln_b + c0);
  float4 lb1 = *reinterpret_cast<const float4*>(ln_b + c1);
  ushort4 o0, o1;
  o0.x = f2bf((yv[0] - mu) * rs * lw0.x + lb0.x);
  o0.y = f2bf((yv[1] - mu) * rs * lw0.y + lb0.y);
  o0.z = f2bf((yv[2] - mu) * rs * lw0.z + lb0.z);
  o0.w = f2bf((yv[3] - mu) * rs * lw0.w + lb0.w);
  o1.x = f2bf((yv[4] - mu) * rs * lw1.x + lb1.x);
  o1.y = f2bf((yv[5] - mu) * rs * lw1.y + lb1.y);
  o1.z = f2bf((yv[6] - mu) * rs * lw1.z + lb1.z);
  o1.w = f2bf((yv[7] - mu) * rs * lw1.w + lb1.w);
  u16* outp = xln + ((size_t)(b * NKP + np)) * DM;
  *reinterpret_cast<ushort4*>(outp + c0) = o0;
  *reinterpret_cast<ushort4*>(outp + c1) = o1;
}

// ---------------- shared GEMM body: C[M,512] = A[M,512]*W[512,512]^T + bias ------------
template <int OMODE>
static __device__ __forceinline__ void gemm_body(const u16* __restrict__ A,
                                                 const u16* __restrict__ Bw,
                                                 const float* __restrict__ bias,
                                                 void* __restrict__ Cptr,
                                                 int nt, int mt,
                                                 u16* Al0, u16* Al1,
                                                 u16* Bl0, u16* Bl1) {
  int wv = threadIdx.x >> 6, lane = threadIdx.x & 63;
  int lr = lane & 15, lg = lane >> 4;
  int wr = wv >> 1, wc = wv & 1;
  int row0 = mt * 128, col0 = nt * 128;

  auto stage = [&](int kk, int bi) {
    u16* Al = bi ? Al1 : Al0;
    u16* Bl = bi ? Bl1 : Bl0;
    #pragma unroll
    for (int i = 0; i < 4; i++) {
      int t = wv * 4 + i;                    // 0..15
      int rr = (t & 7) * 16 + (lane >> 2);
      int cc = lane & 3;
      if (t < 8) {
        gl_lds16(A + (size_t)(row0 + rr) * DM + kk + cc * 8, (char*)Al + t * 1024);
      } else {
        gl_lds16(Bw + (size_t)(col0 + rr) * DM + kk + cc * 8, (char*)Bl + (t - 8) * 1024);
      }
    }
  };

  f32x4 acc[4][4] = {};
  stage(0, 0);
  __syncthreads();
  for (int s = 0; s < 16; s++) {
    int bi = s & 1;
    if (s < 15) stage((s + 1) * 32, bi ^ 1);
    u16* Al = bi ? Al1 : Al0;
    u16* Bl = bi ? Bl1 : Bl0;
    bf16x8 am[4], bn[4];
    #pragma unroll
    for (int m = 0; m < 4; m++)
      am[m] = ld8(Al + (wr * 64 + m * 16 + lr) * 32 + lg * 8);
    #pragma unroll
    for (int n = 0; n < 4; n++)
      bn[n] = ld8(Bl + (wc * 64 + n * 16 + lr) * 32 + lg * 8);
    #pragma unroll
    for (int m = 0; m < 4; m++)
      #pragma unroll
      for (int n = 0; n < 4; n++)
        acc[m][n] = mfma16(am[m], bn[n], acc[m][n]);
    __syncthreads();
  }
  if (OMODE == 2) {
    #pragma unroll
    for (int n = 0; n < 4; n++) {
      int col = col0 + wc * 64 + n * 16 + lr;
      float bs = bias[col];
      #pragma unroll
      for (int m = 0; m < 4; m++) {
        int rbase = row0 + wr * 64 + m * 16 + lg * 4;
        int bb = rbase / NKP;
        int kr = rbase % NKP;          // kr&15 == lg*4
        ushort4 o4;
        o4.x = f2bf(acc[m][n][0] + bs);
        o4.y = f2bf(acc[m][n][1] + bs);
        o4.z = f2bf(acc[m][n][2] + bs);
        o4.w = f2bf(acc[m][n][3] + bs);
        size_t dst = (((size_t)bb * 13 + (kr >> 4)) * 512 + col) * 16 + (kr & 15);
        *reinterpret_cast<ushort4*>(&((u16*)Cptr)[dst]) = o4;
      }
    }
  } else {
    #pragma unroll
    for (int n = 0; n < 4; n++) {
      int col = col0 + wc * 64 + n * 16 + lr;
      float bs = bias[col];
      #pragma unroll
      for (int m = 0; m < 4; m++) {
        #pragma unroll
        for (int r = 0; r < 4; r++) {
          int row = row0 + wr * 64 + m * 16 + lg * 4 + r;
          float v = acc[m][n][r] + bs;
          if (OMODE == 0) {
            ((u16*)Cptr)[(size_t)row * DM + col] = f2bf(v);
          } else {
            ((float*)Cptr)[(size_t)row * DM + col] = v;
          }
        }
      }
    }
  }
}

template <int OMODE>
__global__ __launch_bounds__(256) void gemm2_kernel(const u16* __restrict__ A,
                                                    const u16* __restrict__ Bw,
                                                    const float* __restrict__ bias,
                                                    void* __restrict__ Cptr) {
  __shared__ __align__(16) u16 Al[2][128 * 32];
  __shared__ __align__(16) u16 Bl[2][128 * 32];
  gemm_body<OMODE>(A, Bw, bias, Cptr, blockIdx.x, blockIdx.y,
                   &Al[0][0], &Al[1][0], &Bl[0][0], &Bl[1][0]);
}

// fused K-proj (OMODE 0) + V-proj (OMODE 2): blockIdx.z selects.
__global__ __launch_bounds__(256) void kvgemm_kernel(const u16* __restrict__ A,
                                                     const u16* __restrict__ Wk,
                                                     const float* __restrict__ bk,
                                                     void* __restrict__ Kout,
                                                     const u16* __restrict__ Wv,
                                                     const float* __restrict__ bv,
                                                     void* __restrict__ Vout) {
  __shared__ __align__(16) u16 Al[2][128 * 32];
  __shared__ __align__(16) u16 Bl[2][128 * 32];
  if (blockIdx.z == 0) {
    gemm_body<0>(A, Wk, bk, Kout, blockIdx.x, blockIdx.y,
                 &Al[0][0], &Al[1][0], &Bl[0][0], &Bl[1][0]);
  } else {
    gemm_body<2>(A, Wv, bv, Vout, blockIdx.x, blockIdx.y,
                 &Al[0][0], &Al[1][0], &Bl[0][0], &Bl[1][0]);
  }
}

// ---------------- fused attn: single-buffer Kl (wave-private) + pipelined exchange -----
// grid 1600 XCD-clustered, 4 waves, 32 q-rows per block.
// Round-18: Kl is provably WAVE-PRIVATE (wave wv stages bytes [4wv,4wv+4)KB
// and reads exactly those bytes for its 2 heads) -> single-buffered. The only
// hazard is each wave's own kf ds_reads vs its own gl_lds overwrites: fenced
// by s_waitcnt lgkmcnt(0) + sched_barrier(0) between QK^T and stage (rule
// #18). Staged-data visibility for the next phase comes from the end-of-phase
// __syncthreads vmcnt drain, as before. LDS 64->48KB: 3 blocks/CU (12 waves,
// +50% residency; VGPR 144 allows 3/SIMD).
__global__ __launch_bounds__(256) void attn_kernel(const u16* __restrict__ Q,
                                                   const u16* __restrict__ K,
                                                   const u16* __restrict__ VTt,
                                                   const float* __restrict__ tw,
                                                   u16* __restrict__ Oat) {
  __shared__ __align__(16) u16 Kl[16 * 512];      // 16KB, chunk-major, single buf
  __shared__ __align__(16) float s2[2][16 * 256]; // 2 x 16KB, lane-order tiles
  int i = blockIdx.x;
  int g8 = i & 7;            // XCD group == b%8
  int j = i >> 3;            // 0..199
  int qc = j % 25;
  int b = g8 + 8 * (j / 25);
  int tid = threadIdx.x, wv = tid >> 6, lane = tid & 63;
  int lr = lane & 15, lg = lane >> 4;
  int q0A = qc * 32;
  int q0B = (qc < 24) ? (q0A + 16) : q0A;   // tail duplicates tile A
  int g0 = wv * 2;           // this wave's raw-head pair AND output-head pair

  const u16* Kb = K + (size_t)b * NKP * DM;
  const u16* Vtb = VTt + (size_t)b * 13 * 8192;

  // wave-uniform mixing weights -> SGPRs (1/sqrt(64) folded)
  float w0[8], w1[8];
  #pragma unroll
  for (int h = 0; h < 8; h++) {
    w0[h] = sgpr_f(tw[(g0 + 0) * 8 + h] * 0.125f);
    w1[h] = sgpr_f(tw[(g0 + 1) * 8 + h] * 0.125f);
  }

  // Q fragments REGISTER-resident: only this wave's 2 raw heads x 2 tiles.
  bf16x8 qr[2][2][2];   // [tile][hh][half]
  #pragma unroll
  for (int t = 0; t < 2; t++) {
    const u16* Qb = Q + ((size_t)b * NQ + (t ? q0B : q0A)) * DM;
    #pragma unroll
    for (int hh = 0; hh < 2; hh++) {
      qr[t][hh][0] = ld8(Qb + (size_t)lr * DM + (g0 + hh) * 64 + lg * 8);
      qr[t][hh][1] = ld8(Qb + (size_t)lr * DM + (g0 + hh) * 64 + 32 + lg * 8);
    }
  }

  // chunk-major staging into the wave's PRIVATE quarter: groups g = wv*4..+3
  // cover bytes [wv*4KB, wv*4KB+4KB) == the d-chunks of heads {2wv, 2wv+1}.
  auto stageK = [&](int kt) {
    #pragma unroll
    for (int i2 = 0; i2 < 4; i2++) {
      int g = wv * 4 + i2;
      gl_lds16(Kb + (size_t)(kt * 16 + (lane & 15)) * DM + (g * 4 + (lane >> 4)) * 8,
               (char*)Kl + g * 1024);
    }
  };
  stageK(0);
  __syncthreads();

  f32x4 o[2][2][4] = {};      // [tile][g][j]
  float sumA0 = 0.f, sumA1 = 0.f, sumB0 = 0.f, sumB1 = 0.f;
  s16x4 vb[2][4];

  // mix + exp + PV for k-tile ktm, scores in s2[sbi]
  auto mixpv = [&](int ktm, int sbi) {
    bool masked = (ktm == 12) && (lg != 0);   // k >= 196
    s16x4 pa[2][2];
    #pragma unroll
    for (int t = 0; t < 2; t++) {
      f32x4 sa = {0.f, 0.f, 0.f, 0.f};
      f32x4 sb = {0.f, 0.f, 0.f, 0.f};
      #pragma unroll
      for (int h = 0; h < 8; h++) {
        f32x4 scv = *reinterpret_cast<const f32x4*>(
            &s2[sbi][0] + (t * 8 + h) * 256 + lane * 4);
        sa += scv * w0[h];
        sb += scv * w1[h];
      }
      float e0 = masked ? 0.f : __expf(sa[0]);
      float e1 = masked ? 0.f : __expf(sa[1]);
      float e2 = masked ? 0.f : __expf(sa[2]);
      float e3 = masked ? 0.f : __expf(sa[3]);
      float f0 = masked ? 0.f : __expf(sb[0]);
      float f1 = masked ? 0.f : __expf(sb[1]);
      float f2 = masked ? 0.f : __expf(sb[2]);
      float f3 = masked ? 0.f : __expf(sb[3]);
      if (t == 0) {
        sumA0 += (e0 + e1) + (e2 + e3);
        sumA1 += (f0 + f1) + (f2 + f3);
      } else {
        sumB0 += (e0 + e1) + (e2 + e3);
        sumB1 += (f0 + f1) + (f2 + f3);
      }
      union { __bf16 e[4]; s16x4 sv; } pk;
      pk.e[0] = (__bf16)e0; pk.e[1] = (__bf16)e1;
      pk.e[2] = (__bf16)e2; pk.e[3] = (__bf16)e3;
      pa[t][0] = pk.sv;
      pk.e[0] = (__bf16)f0; pk.e[1] = (__bf16)f1;
      pk.e[2] = (__bf16)f2; pk.e[3] = (__bf16)f3;
      pa[t][1] = pk.sv;
    }
    __builtin_amdgcn_s_setprio(1);
    #pragma unroll
    for (int t = 0; t < 2; t++) {
      #pragma unroll
      for (int gi = 0; gi < 2; gi++) {
        #pragma unroll
        for (int j2 = 0; j2 < 4; j2++)
          o[t][gi][j2] = mfma16k16(pa[t][gi], vb[gi][j2], o[t][gi][j2]);
      }
    }
    __builtin_amdgcn_s_setprio(0);
  };

  for (int kt = 0; kt < 13; kt++) {
    int bi = kt & 1;

    // EARLY V for the pipelined mix/PV of kt-1 (latency hidden under QK^T)
    if (kt > 0) {
      #pragma unroll
      for (int gi = 0; gi < 2; gi++) {
        #pragma unroll
        for (int j2 = 0; j2 < 4; j2++) {
          int d = (g0 + gi) * 64 + j2 * 16 + lr;
          vb[gi][j2] = *reinterpret_cast<const s16x4*>(
              Vtb + (size_t)(kt - 1) * 8192 + d * 16 + lg * 4);
        }
      }
    }

    // QK^T(kt) for this wave's 2 raw heads, both tiles; write s2[bi]
    const u16* kbase = Kl + lg * 128 + lr * 8;
    __builtin_amdgcn_s_setprio(1);
    #pragma unroll
    for (int hh = 0; hh < 2; hh++) {
      bf16x8 kf0 = ld8(kbase + (g0 + hh) * 1024);
      bf16x8 kf1 = ld8(kbase + (g0 + hh) * 1024 + 512);
      #pragma unroll
      for (int t = 0; t < 2; t++) {
        f32x4 tt = {0.f, 0.f, 0.f, 0.f};
        tt = mfma16(kf0, qr[t][hh][0], tt);
        tt = mfma16(kf1, qr[t][hh][1], tt);
        *reinterpret_cast<f32x4*>(&s2[bi][0] + (t * 8 + g0 + hh) * 256 + lane * 4) = tt;
      }
    }
    __builtin_amdgcn_s_setprio(0);

    // fence: all kf ds_reads retired before this wave overwrites its quarter
    asm volatile("s_waitcnt lgkmcnt(0)" ::: "memory");
    __builtin_amdgcn_sched_barrier(0);
    if (kt < 12) stageK(kt + 1);

    // pipelined mix/exp/PV for kt-1 (scores from s2[bi^1], visible since
    // the barrier at the end of iteration kt-1)
    if (kt > 0) mixpv(kt - 1, bi ^ 1);

    __syncthreads();   // drains stage(kt+1) writes; s2[bi] visible for iter kt+1
  }
  // epilogue: mix/PV for kt=12 (scores in s2[0], visible after last barrier)
  {
    #pragma unroll
    for (int gi = 0; gi < 2; gi++) {
      #pragma unroll
      for (int j2 = 0; j2 < 4; j2++) {
        int d = (g0 + gi) * 64 + j2 * 16 + lr;
        vb[gi][j2] = *reinterpret_cast<const s16x4*>(
            Vtb + (size_t)12 * 8192 + d * 16 + lg * 4);
      }
    }
    mixpv(12, 0);
  }

  // complete row sums (k split across lane groups 16 apart)
  sumA0 += __shfl_xor(sumA0, 16); sumA0 += __shfl_xor(sumA0, 32);
  sumA1 += __shfl_xor(sumA1, 16); sumA1 += __shfl_xor(sumA1, 32);
  sumB0 += __shfl_xor(sumB0, 16); sumB0 += __shfl_xor(sumB0, 32);
  sumB1 += __shfl_xor(sumB1, 16); sumB1 += __shfl_xor(sumB1, 32);
  float ivA0 = 1.0f / sumA0, ivA1 = 1.0f / sumA1;
  float ivB0 = 1.0f / sumB0, ivB1 = 1.0f / sumB1;
  #pragma unroll
  for (int t = 0; t < 2; t++) {
    if (t == 1 && qc == 24) break;   // tail: tile B is a duplicate
    int q0 = t ? q0B : q0A;
    #pragma unroll
    for (int gi = 0; gi < 2; gi++) {
      int g = g0 + gi;
      float ivsrc = t ? (gi ? ivB1 : ivB0) : (gi ? ivA1 : ivA0);
      #pragma unroll
      for (int r = 0; r < 4; r++) {
        int q = lg * 4 + r;
        float iv = __shfl(ivsrc, q);   // sum lives at lane lr == q
        #pragma unroll
        for (int j2 = 0; j2 < 4; j2++) {
          Oat[((size_t)(b * NQ + q0 + q)) * DM + g * 64 + j2 * 16 + lr] =
              f2bf(o[t][gi][j2][r] * iv);
        }
      }
    }
  }
}

// ---------------- launch ----------------
extern "C" void kernel_launch(void* const* d_in, const int* in_sizes, int n_in,
                              void* d_out, int out_size, void* d_ws, size_t ws_size,
                              hipStream_t stream) {
  const float* queries = (const float*)d_in[0];
  const float* Wq = (const float*)d_in[3];
  const float* bq = (const float*)d_in[4];
  const float* Wk = (const float*)d_in[5];
  const float* bk = (const float*)d_in[6];
  const float* Wv = (const float*)d_in[7];
  const float* bv = (const float*)d_in[8];
  const float* Wo = (const float*)d_in[9];
  const float* bo = (const float*)d_in[10];
  const float* sr_w = (const float*)d_in[11];
  const float* sr_b = (const float*)d_in[12];
  const float* ln_w = (const float*)d_in[13];
  const float* ln_b = (const float*)d_in[14];
  const float* tw = (const float*)d_in[15];

  char* ws = (char*)d_ws;
  u16* wq_bf = (u16*)(ws + 0);          // 512KB
  u16* wk_bf = (u16*)(ws + 524288);
  u16* wv_bf = (u16*)(ws + 1048576);
  u16* wo_bf = (u16*)(ws + 1572864);
  u16* xln   = (u16*)(ws + 2097152);    // 64*208*512*2 = 13,631,488
  u16* Kbuf  = (u16*)(ws + 15728640);   // 13,631,488
  u16* VTt   = (u16*)(ws + 29360128);   // 64*13*512*16*2 = 13,631,488
  u16* Qbuf  = (u16*)(ws + 42991616);   // 64*784*512*2 = 51,380,224
  u16* qbf   = (u16*)(ws + 94371840);   // 51,380,224 -> end 145,752,064
  u16* Oat   = qbf;                     // qbf dead after Q-proj; attn reuses it
  if (ws_size < 145752064u) return;     // fail loudly (output stays poisoned)

  // all 4 weight conversions in ONE launch (1024 blocks)
  cvt4_kernel<<<1024, 256, 0, stream>>>(Wq, Wk, Wv, Wo,
                                        wq_bf, wk_bf, wv_bf, wo_bf);

  // fused queries cvt + LN: 64*784 + 64*12 waves
  cvtln_kernel<<<(NB * NQ + NB * 12 + 3) / 4, 256, 0, stream>>>(
      queries, sr_w, sr_b, ln_w, ln_b, qbf, xln);

  // Q = qbf @ Wq^T + bq   M = 50176
  gemm2_kernel<0><<<dim3(4, 392), 256, 0, stream>>>(qbf, wq_bf, bq, Qbuf);
  // K-proj + V-proj fused (z=0: K [row][col] bf16; z=1: V tiled)
  kvgemm_kernel<<<dim3(4, 104, 2), 256, 0, stream>>>(xln, wk_bf, bk, Kbuf,
                                                     wv_bf, bv, VTt);

  attn_kernel<<<dim3(1600), 256, 0, stream>>>(Qbuf, Kbuf, VTt, tw, Oat);

  // out = Oat @ Wo^T + bo  (fp32 out)
  gemm2_kernel<1><<<dim3(4, 392), 256, 0, stream>>>(Oat, wo_bf, bo, d_out);
}

// Round 19
// 259.335 us; speedup vs baseline: 1.2669x; 1.1475x over previous
//
#include <hip/hip_runtime.h>
#include <stdint.h>

typedef unsigned short u16;
typedef unsigned int   u32;
typedef __attribute__((ext_vector_type(8))) __bf16 bf16x8;
typedef __attribute__((ext_vector_type(4))) float  f32x4;
typedef __attribute__((ext_vector_type(4))) short  s16x4;

#define NB  64
#define NQ  784
#define NK  196
#define NKP 208      // nk padded to 13*16
#define DM  512

static __device__ inline u16 f2bf(float f) {
  u32 u = __float_as_uint(f);
  u32 r = (u + 0x7fffu + ((u >> 16) & 1u)) >> 16;
  return (u16)r;
}

static __device__ inline bf16x8 ld8(const u16* p) {
  return *reinterpret_cast<const bf16x8*>(p);
}
static __device__ inline f32x4 mfma16(bf16x8 a, bf16x8 b, f32x4 c) {
  return __builtin_amdgcn_mfma_f32_16x16x32_bf16(a, b, c, 0, 0, 0);
}
// K=16 bf16 MFMA (4 bf16 per lane per operand)
static __device__ inline f32x4 mfma16k16(s16x4 a, s16x4 b, f32x4 c) {
#if __has_builtin(__builtin_amdgcn_mfma_f32_16x16x16bf16_1k)
  return __builtin_amdgcn_mfma_f32_16x16x16bf16_1k(a, b, c, 0, 0, 0);
#elif __has_builtin(__builtin_amdgcn_mfma_f32_16x16x16_bf16)
  typedef __attribute__((ext_vector_type(4))) __bf16 bf16x4_t;
  union { s16x4 s; bf16x4_t b; } ua, ub;
  ua.s = a; ub.s = b;
  return __builtin_amdgcn_mfma_f32_16x16x16_bf16(ua.b, ub.b, c, 0, 0, 0);
#else
  asm volatile("v_mfma_f32_16x16x16_bf16 %0, %1, %2, %0\n\ts_nop 7\n\ts_nop 7"
               : "+v"(c) : "v"(a), "v"(b));
  return c;
#endif
}

// wave-uniform float -> SGPR
static __device__ inline float sgpr_f(float x) {
  return __uint_as_float(__builtin_amdgcn_readfirstlane(__float_as_uint(x)));
}

// async global -> LDS, 16B per lane; LDS dest must be wave-uniform base
static __device__ inline void gl_lds16(const void* g, void* l) {
  __builtin_amdgcn_global_load_lds(
      (const __attribute__((address_space(1))) void*)g,
      (__attribute__((address_space(3))) void*)l, 16, 0, 0);
}

// ---------------- fused fp32 -> bf16 conversion of the 4 weight matrices ---------------
__global__ __launch_bounds__(256) void cvt4_kernel(const float* __restrict__ Wq,
                                                   const float* __restrict__ Wk,
                                                   const float* __restrict__ Wv,
                                                   const float* __restrict__ Wo,
                                                   u16* __restrict__ oq,
                                                   u16* __restrict__ ok,
                                                   u16* __restrict__ ov,
                                                   u16* __restrict__ oo) {
  int sel = blockIdx.x >> 8;
  int blk = blockIdx.x & 255;
  const float* in = (sel == 0) ? Wq : (sel == 1) ? Wk : (sel == 2) ? Wv : Wo;
  u16* out = (sel == 0) ? oq : (sel == 1) ? ok : (sel == 2) ? ov : oo;
  int i = (blk * 256 + threadIdx.x) * 4;
  float4 f = *reinterpret_cast<const float4*>(in + i);
  ushort4 o;
  o.x = f2bf(f.x); o.y = f2bf(f.y); o.z = f2bf(f.z); o.w = f2bf(f.w);
  *reinterpret_cast<ushort4*>(out + i) = o;
}

// ---------------- fused queries cvt (fp32->bf16) + spatial-reduce LayerNorm ------------
__global__ __launch_bounds__(256) void cvtln_kernel(const float* __restrict__ q,
                                                    const float* __restrict__ sr_w,
                                                    const float* __restrict__ sr_b,
                                                    const float* __restrict__ ln_w,
                                                    const float* __restrict__ ln_b,
                                                    u16* __restrict__ qbf,
                                                    u16* __restrict__ xln) {
  int w = blockIdx.x * 4 + (threadIdx.x >> 6);
  int lane = threadIdx.x & 63;
  if (w >= NB * NQ) {
    int w2 = w - NB * NQ;
    if (w2 < NB * 12) {
      int b = w2 / 12, pr = w2 % 12;
      u16* outp = xln + ((size_t)(b * NKP + NK + pr)) * DM;
      *reinterpret_cast<uint4*>(outp + lane * 8) = make_uint4(0u, 0u, 0u, 0u);
    }
    return;
  }
  int b = w / NQ, n = w % NQ;
  const float* row = q + ((size_t)w) * DM;
  int c0 = lane * 4, c1 = 256 + lane * 4;
  float4 x0 = *reinterpret_cast<const float4*>(row + c0);
  float4 x1 = *reinterpret_cast<const float4*>(row + c1);
  u16* qp = qbf + (size_t)w * DM;
  ushort4 q0, q1;
  q0.x = f2bf(x0.x); q0.y = f2bf(x0.y); q0.z = f2bf(x0.z); q0.w = f2bf(x0.w);
  q1.x = f2bf(x1.x); q1.y = f2bf(x1.y); q1.z = f2bf(x1.z); q1.w = f2bf(x1.w);
  *reinterpret_cast<ushort4*>(qp + c0) = q0;
  *reinterpret_cast<ushort4*>(qp + c1) = q1;
  int y = n / 28, x = n % 28;
  if ((y & 1) | (x & 1)) return;
  int np = (y >> 1) * 14 + (x >> 1);
  float4 w0 = *reinterpret_cast<const float4*>(sr_w + c0);
  float4 w1 = *reinterpret_cast<const float4*>(sr_w + c1);
  float4 s0 = *reinterpret_cast<const float4*>(sr_b + c0);
  float4 s1 = *reinterpret_cast<const float4*>(sr_b + c1);
  float yv[8];
  yv[0] = x0.x * w0.x + s0.x; yv[1] = x0.y * w0.y + s0.y;
  yv[2] = x0.z * w0.z + s0.z; yv[3] = x0.w * w0.w + s0.w;
  yv[4] = x1.x * w1.x + s1.x; yv[5] = x1.y * w1.y + s1.y;
  yv[6] = x1.z * w1.z + s1.z; yv[7] = x1.w * w1.w + s1.w;
  float s = 0.f, ss = 0.f;
  #pragma unroll
  for (int i = 0; i < 8; i++) { s += yv[i]; ss += yv[i] * yv[i]; }
  #pragma unroll
  for (int off = 1; off < 64; off <<= 1) {
    s += __shfl_xor(s, off); ss += __shfl_xor(ss, off);
  }
  float mu = s * (1.f / 512.f);
  float var = ss * (1.f / 512.f) - mu * mu;
  float rs = rsqrtf(var + 1e-5f);
  float4 lw0 = *reinterpret_cast<const float4*>(ln_w + c0);
  float4 lw1 = *reinterpret_cast<const float4*>(ln_w + c1);
  float4 lb0 = *reinterpret_cast<const float4*>(ln_b + c0);
  float4 lb1 = *reinterpret_cast<const float4*>(ln_b + c1);
  ushort4 o0, o1;
  o0.x = f2bf((yv[0] - mu) * rs * lw0.x + lb0.x);
  o0.y = f2bf((yv[1] - mu) * rs * lw0.y + lb0.y);
  o0.z = f2bf((yv[2] - mu) * rs * lw0.z + lb0.z);
  o0.w = f2bf((yv[3] - mu) * rs * lw0.w + lb0.w);
  o1.x = f2bf((yv[4] - mu) * rs * lw1.x + lb1.x);
  o1.y = f2bf((yv[5] - mu) * rs * lw1.y + lb1.y);
  o1.z = f2bf((yv[6] - mu) * rs * lw1.z + lb1.z);
  o1.w = f2bf((yv[7] - mu) * rs * lw1.w + lb1.w);
  u16* outp = xln + ((size_t)(b * NKP + np)) * DM;
  *reinterpret_cast<ushort4*>(outp + c0) = o0;
  *reinterpret_cast<ushort4*>(outp + c1) = o1;
}

// ---------------- shared GEMM body: C[M,512] = A[M,512]*W[512,512]^T + bias ------------
template <int OMODE>
static __device__ __forceinline__ void gemm_body(const u16* __restrict__ A,
                                                 const u16* __restrict__ Bw,
                                                 const float* __restrict__ bias,
                                                 void* __restrict__ Cptr,
                                                 int nt, int mt,
                                                 u16* Al0, u16* Al1,
                                                 u16* Bl0, u16* Bl1) {
  int wv = threadIdx.x >> 6, lane = threadIdx.x & 63;
  int lr = lane & 15, lg = lane >> 4;
  int wr = wv >> 1, wc = wv & 1;
  int row0 = mt * 128, col0 = nt * 128;

  auto stage = [&](int kk, int bi) {
    u16* Al = bi ? Al1 : Al0;
    u16* Bl = bi ? Bl1 : Bl0;
    #pragma unroll
    for (int i = 0; i < 4; i++) {
      int t = wv * 4 + i;                    // 0..15
      int rr = (t & 7) * 16 + (lane >> 2);
      int cc = lane & 3;
      if (t < 8) {
        gl_lds16(A + (size_t)(row0 + rr) * DM + kk + cc * 8, (char*)Al + t * 1024);
      } else {
        gl_lds16(Bw + (size_t)(col0 + rr) * DM + kk + cc * 8, (char*)Bl + (t - 8) * 1024);
      }
    }
  };

  f32x4 acc[4][4] = {};
  stage(0, 0);
  __syncthreads();
  for (int s = 0; s < 16; s++) {
    int bi = s & 1;
    if (s < 15) stage((s + 1) * 32, bi ^ 1);
    u16* Al = bi ? Al1 : Al0;
    u16* Bl = bi ? Bl1 : Bl0;
    bf16x8 am[4], bn[4];
    #pragma unroll
    for (int m = 0; m < 4; m++)
      am[m] = ld8(Al + (wr * 64 + m * 16 + lr) * 32 + lg * 8);
    #pragma unroll
    for (int n = 0; n < 4; n++)
      bn[n] = ld8(Bl + (wc * 64 + n * 16 + lr) * 32 + lg * 8);
    #pragma unroll
    for (int m = 0; m < 4; m++)
      #pragma unroll
      for (int n = 0; n < 4; n++)
        acc[m][n] = mfma16(am[m], bn[n], acc[m][n]);
    __syncthreads();
  }
  if (OMODE == 2) {
    #pragma unroll
    for (int n = 0; n < 4; n++) {
      int col = col0 + wc * 64 + n * 16 + lr;
      float bs = bias[col];
      #pragma unroll
      for (int m = 0; m < 4; m++) {
        int rbase = row0 + wr * 64 + m * 16 + lg * 4;
        int bb = rbase / NKP;
        int kr = rbase % NKP;          // kr&15 == lg*4
        ushort4 o4;
        o4.x = f2bf(acc[m][n][0] + bs);
        o4.y = f2bf(acc[m][n][1] + bs);
        o4.z = f2bf(acc[m][n][2] + bs);
        o4.w = f2bf(acc[m][n][3] + bs);
        size_t dst = (((size_t)bb * 13 + (kr >> 4)) * 512 + col) * 16 + (kr & 15);
        *reinterpret_cast<ushort4*>(&((u16*)Cptr)[dst]) = o4;
      }
    }
  } else {
    #pragma unroll
    for (int n = 0; n < 4; n++) {
      int col = col0 + wc * 64 + n * 16 + lr;
      float bs = bias[col];
      #pragma unroll
      for (int m = 0; m < 4; m++) {
        #pragma unroll
        for (int r = 0; r < 4; r++) {
          int row = row0 + wr * 64 + m * 16 + lg * 4 + r;
          float v = acc[m][n][r] + bs;
          if (OMODE == 0) {
            ((u16*)Cptr)[(size_t)row * DM + col] = f2bf(v);
          } else {
            ((float*)Cptr)[(size_t)row * DM + col] = v;
          }
        }
      }
    }
  }
}

template <int OMODE>
__global__ __launch_bounds__(256) void gemm2_kernel(const u16* __restrict__ A,
                                                    const u16* __restrict__ Bw,
                                                    const float* __restrict__ bias,
                                                    void* __restrict__ Cptr) {
  __shared__ __align__(16) u16 Al[2][128 * 32];
  __shared__ __align__(16) u16 Bl[2][128 * 32];
  gemm_body<OMODE>(A, Bw, bias, Cptr, blockIdx.x, blockIdx.y,
                   &Al[0][0], &Al[1][0], &Bl[0][0], &Bl[1][0]);
}

// fused K-proj (OMODE 0) + V-proj (OMODE 2): blockIdx.z selects.
__global__ __launch_bounds__(256) void kvgemm_kernel(const u16* __restrict__ A,
                                                     const u16* __restrict__ Wk,
                                                     const float* __restrict__ bk,
                                                     void* __restrict__ Kout,
                                                     const u16* __restrict__ Wv,
                                                     const float* __restrict__ bv,
                                                     void* __restrict__ Vout) {
  __shared__ __align__(16) u16 Al[2][128 * 32];
  __shared__ __align__(16) u16 Bl[2][128 * 32];
  if (blockIdx.z == 0) {
    gemm_body<0>(A, Wk, bk, Kout, blockIdx.x, blockIdx.y,
                 &Al[0][0], &Al[1][0], &Bl[0][0], &Bl[1][0]);
  } else {
    gemm_body<2>(A, Wv, bv, Vout, blockIdx.x, blockIdx.y,
                 &Al[0][0], &Al[1][0], &Bl[0][0], &Bl[1][0]);
  }
}

// ---------------- fused attn: 512 threads, 8 waves, ONE head per wave ------------------
// Round-19: same dedup + one-barrier pipelined score exchange as r17/r18, but
// 8 waves x 1 raw head / 1 output head each. Per-wave register state halves
// (qr 16, o 32, vb 8, pa 4 -> ~100 VGPR < the 128 cliff from m69's
// waves-halve-at-{64,128,256} quantization that nullified r18's LDS cut at
// VGPR=144). LDS 48KB (Kl 16 + s2 2x16) -> 2 blocks x 8 waves = 16 waves/CU,
// 2x round-18 residency. Wave-private Kl staging (wave wv stages groups
// {2wv,2wv+1} = head wv's d-chunks), lgkmcnt fence, lane-order s2.
__global__ __launch_bounds__(512) void attn_kernel(const u16* __restrict__ Q,
                                                   const u16* __restrict__ K,
                                                   const u16* __restrict__ VTt,
                                                   const float* __restrict__ tw,
                                                   u16* __restrict__ Oat) {
  __shared__ __align__(16) u16 Kl[16 * 512];      // 16KB, chunk-major, single buf
  __shared__ __align__(16) float s2[2][16 * 256]; // 2 x 16KB, lane-order tiles
  int i = blockIdx.x;
  int g8 = i & 7;            // XCD group == b%8
  int j = i >> 3;            // 0..199
  int qc = j % 25;
  int b = g8 + 8 * (j / 25);
  int tid = threadIdx.x, wv = tid >> 6, lane = tid & 63;
  int lr = lane & 15, lg = lane >> 4;
  int q0A = qc * 32;
  int q0B = (qc < 24) ? (q0A + 16) : q0A;   // tail duplicates tile A
  // wave wv owns raw head wv AND output head wv

  const u16* Kb = K + (size_t)b * NKP * DM;
  const u16* Vtb = VTt + (size_t)b * 13 * 8192;

  // wave-uniform mixing weights for output head wv -> SGPRs (1/sqrt(64) folded)
  float w0[8];
  #pragma unroll
  for (int h = 0; h < 8; h++)
    w0[h] = sgpr_f(tw[wv * 8 + h] * 0.125f);

  // Q fragments REGISTER-resident: raw head wv x 2 tiles x 2 halves (16 VGPR)
  bf16x8 qr[2][2];   // [tile][half]
  #pragma unroll
  for (int t = 0; t < 2; t++) {
    const u16* Qb = Q + ((size_t)b * NQ + (t ? q0B : q0A)) * DM;
    qr[t][0] = ld8(Qb + (size_t)lr * DM + wv * 64 + lg * 8);
    qr[t][1] = ld8(Qb + (size_t)lr * DM + wv * 64 + 32 + lg * 8);
  }

  // chunk-major staging into the wave's PRIVATE eighth: groups g = wv*2, wv*2+1
  // cover bytes [wv*2KB, wv*2KB+2KB) == head wv's d-chunks.
  auto stageK = [&](int kt) {
    #pragma unroll
    for (int i2 = 0; i2 < 2; i2++) {
      int g = wv * 2 + i2;
      gl_lds16(Kb + (size_t)(kt * 16 + (lane & 15)) * DM + (g * 4 + (lane >> 4)) * 8,
               (char*)Kl + g * 1024);
    }
  };
  stageK(0);
  __syncthreads();

  f32x4 o[2][4] = {};      // [tile][j]
  float sumA = 0.f, sumB = 0.f;
  s16x4 vb[4];

  // mix + exp + PV for k-tile ktm, scores in s2[sbi]
  auto mixpv = [&](int ktm, int sbi) {
    bool masked = (ktm == 12) && (lg != 0);   // k >= 196
    s16x4 pa[2];
    #pragma unroll
    for (int t = 0; t < 2; t++) {
      f32x4 sa = {0.f, 0.f, 0.f, 0.f};
      #pragma unroll
      for (int h = 0; h < 8; h++) {
        f32x4 scv = *reinterpret_cast<const f32x4*>(
            &s2[sbi][0] + (t * 8 + h) * 256 + lane * 4);
        sa += scv * w0[h];
      }
      float e0 = masked ? 0.f : __expf(sa[0]);
      float e1 = masked ? 0.f : __expf(sa[1]);
      float e2 = masked ? 0.f : __expf(sa[2]);
      float e3 = masked ? 0.f : __expf(sa[3]);
      if (t == 0) sumA += (e0 + e1) + (e2 + e3);
      else        sumB += (e0 + e1) + (e2 + e3);
      union { __bf16 e[4]; s16x4 sv; } pk;
      pk.e[0] = (__bf16)e0; pk.e[1] = (__bf16)e1;
      pk.e[2] = (__bf16)e2; pk.e[3] = (__bf16)e3;
      pa[t] = pk.sv;
    }
    __builtin_amdgcn_s_setprio(1);
    #pragma unroll
    for (int t = 0; t < 2; t++) {
      #pragma unroll
      for (int j2 = 0; j2 < 4; j2++)
        o[t][j2] = mfma16k16(pa[t], vb[j2], o[t][j2]);
    }
    __builtin_amdgcn_s_setprio(0);
  };

  for (int kt = 0; kt < 13; kt++) {
    int bi = kt & 1;

    // EARLY V for the pipelined mix/PV of kt-1 (latency hidden under QK^T)
    if (kt > 0) {
      #pragma unroll
      for (int j2 = 0; j2 < 4; j2++) {
        int d = wv * 64 + j2 * 16 + lr;
        vb[j2] = *reinterpret_cast<const s16x4*>(
            Vtb + (size_t)(kt - 1) * 8192 + d * 16 + lg * 4);
      }
    }

    // QK^T(kt) for raw head wv, both tiles; write s2[bi]
    const u16* kbase = Kl + lg * 128 + lr * 8;
    __builtin_amdgcn_s_setprio(1);
    {
      bf16x8 kf0 = ld8(kbase + wv * 1024);
      bf16x8 kf1 = ld8(kbase + wv * 1024 + 512);
      #pragma unroll
      for (int t = 0; t < 2; t++) {
        f32x4 tt = {0.f, 0.f, 0.f, 0.f};
        tt = mfma16(kf0, qr[t][0], tt);
        tt = mfma16(kf1, qr[t][1], tt);
        *reinterpret_cast<f32x4*>(&s2[bi][0] + (t * 8 + wv) * 256 + lane * 4) = tt;
      }
    }
    __builtin_amdgcn_s_setprio(0);

    // fence: all kf ds_reads retired before this wave overwrites its eighth
    asm volatile("s_waitcnt lgkmcnt(0)" ::: "memory");
    __builtin_amdgcn_sched_barrier(0);
    if (kt < 12) stageK(kt + 1);

    // pipelined mix/exp/PV for kt-1 (scores from s2[bi^1])
    if (kt > 0) mixpv(kt - 1, bi ^ 1);

    __syncthreads();   // drains stage(kt+1) writes; s2[bi] visible for iter kt+1
  }
  // epilogue: mix/PV for kt=12 (scores in s2[0], visible after last barrier)
  {
    #pragma unroll
    for (int j2 = 0; j2 < 4; j2++) {
      int d = wv * 64 + j2 * 16 + lr;
      vb[j2] = *reinterpret_cast<const s16x4*>(
          Vtb + (size_t)12 * 8192 + d * 16 + lg * 4);
    }
    mixpv(12, 0);
  }

  // complete row sums (k split across lane groups 16 apart)
  sumA += __shfl_xor(sumA, 16); sumA += __shfl_xor(sumA, 32);
  sumB += __shfl_xor(sumB, 16); sumB += __shfl_xor(sumB, 32);
  float ivA = 1.0f / sumA, ivB = 1.0f / sumB;
  #pragma unroll
  for (int t = 0; t < 2; t++) {
    if (t == 1 && qc == 24) break;   // tail: tile B is a duplicate
    int q0 = t ? q0B : q0A;
    float ivsrc = t ? ivB : ivA;
    #pragma unroll
    for (int r = 0; r < 4; r++) {
      int q = lg * 4 + r;
      float iv = __shfl(ivsrc, q);   // sum lives at lane lr == q
      #pragma unroll
      for (int j2 = 0; j2 < 4; j2++) {
        Oat[((size_t)(b * NQ + q0 + q)) * DM + wv * 64 + j2 * 16 + lr] =
            f2bf(o[t][j2][r] * iv);
      }
    }
  }
}

// ---------------- launch ----------------
extern "C" void kernel_launch(void* const* d_in, const int* in_sizes, int n_in,
                              void* d_out, int out_size, void* d_ws, size_t ws_size,
                              hipStream_t stream) {
  const float* queries = (const float*)d_in[0];
  const float* Wq = (const float*)d_in[3];
  const float* bq = (const float*)d_in[4];
  const float* Wk = (const float*)d_in[5];
  const float* bk = (const float*)d_in[6];
  const float* Wv = (const float*)d_in[7];
  const float* bv = (const float*)d_in[8];
  const float* Wo = (const float*)d_in[9];
  const float* bo = (const float*)d_in[10];
  const float* sr_w = (const float*)d_in[11];
  const float* sr_b = (const float*)d_in[12];
  const float* ln_w = (const float*)d_in[13];
  const float* ln_b = (const float*)d_in[14];
  const float* tw = (const float*)d_in[15];

  char* ws = (char*)d_ws;
  u16* wq_bf = (u16*)(ws + 0);          // 512KB
  u16* wk_bf = (u16*)(ws + 524288);
  u16* wv_bf = (u16*)(ws + 1048576);
  u16* wo_bf = (u16*)(ws + 1572864);
  u16* xln   = (u16*)(ws + 2097152);    // 64*208*512*2 = 13,631,488
  u16* Kbuf  = (u16*)(ws + 15728640);   // 13,631,488
  u16* VTt   = (u16*)(ws + 29360128);   // 64*13*512*16*2 = 13,631,488
  u16* Qbuf  = (u16*)(ws + 42991616);   // 64*784*512*2 = 51,380,224
  u16* qbf   = (u16*)(ws + 94371840);   // 51,380,224 -> end 145,752,064
  u16* Oat   = qbf;                     // qbf dead after Q-proj; attn reuses it
  if (ws_size < 145752064u) return;     // fail loudly (output stays poisoned)

  // all 4 weight conversions in ONE launch (1024 blocks)
  cvt4_kernel<<<1024, 256, 0, stream>>>(Wq, Wk, Wv, Wo,
                                        wq_bf, wk_bf, wv_bf, wo_bf);

  // fused queries cvt + LN: 64*784 + 64*12 waves
  cvtln_kernel<<<(NB * NQ + NB * 12 + 3) / 4, 256, 0, stream>>>(
      queries, sr_w, sr_b, ln_w, ln_b, qbf, xln);

  // Q = qbf @ Wq^T + bq   M = 50176
  gemm2_kernel<0><<<dim3(4, 392), 256, 0, stream>>>(qbf, wq_bf, bq, Qbuf);
  // K-proj + V-proj fused (z=0: K [row][col] bf16; z=1: V tiled)
  kvgemm_kernel<<<dim3(4, 104, 2), 256, 0, stream>>>(xln, wk_bf, bk, Kbuf,
                                                     wv_bf, bv, VTt);

  attn_kernel<<<dim3(1600), 512, 0, stream>>>(Qbuf, Kbuf, VTt, tw, Oat);

  // out = Oat @ Wo^T + bo  (fp32 out)
  gemm2_kernel<1><<<dim3(4, 392), 256, 0, stream>>>(Oat, wo_bf, bo, d_out);
}

// Round 20
// 233.992 us; speedup vs baseline: 1.4041x; 1.1083x over previous
//
#include <hip/hip_runtime.h>
#include <stdint.h>

typedef unsigned short u16;
typedef unsigned int   u32;
typedef __attribute__((ext_vector_type(8))) __bf16 bf16x8;
typedef __attribute__((ext_vector_type(4))) float  f32x4;
typedef __attribute__((ext_vector_type(4))) short  s16x4;

#define NB  64
#define NQ  784
#define NK  196
#define NKP 208      // nk padded to 13*16
#define DM  512

static __device__ inline u16 f2bf(float f) {
  u32 u = __float_as_uint(f);
  u32 r = (u + 0x7fffu + ((u >> 16) & 1u)) >> 16;
  return (u16)r;
}

static __device__ inline bf16x8 ld8(const u16* p) {
  return *reinterpret_cast<const bf16x8*>(p);
}
static __device__ inline f32x4 mfma16(bf16x8 a, bf16x8 b, f32x4 c) {
  return __builtin_amdgcn_mfma_f32_16x16x32_bf16(a, b, c, 0, 0, 0);
}
// K=16 bf16 MFMA (4 bf16 per lane per operand)
static __device__ inline f32x4 mfma16k16(s16x4 a, s16x4 b, f32x4 c) {
#if __has_builtin(__builtin_amdgcn_mfma_f32_16x16x16bf16_1k)
  return __builtin_amdgcn_mfma_f32_16x16x16bf16_1k(a, b, c, 0, 0, 0);
#elif __has_builtin(__builtin_amdgcn_mfma_f32_16x16x16_bf16)
  typedef __attribute__((ext_vector_type(4))) __bf16 bf16x4_t;
  union { s16x4 s; bf16x4_t b; } ua, ub;
  ua.s = a; ub.s = b;
  return __builtin_amdgcn_mfma_f32_16x16x16_bf16(ua.b, ub.b, c, 0, 0, 0);
#else
  asm volatile("v_mfma_f32_16x16x16_bf16 %0, %1, %2, %0\n\ts_nop 7\n\ts_nop 7"
               : "+v"(c) : "v"(a), "v"(b));
  return c;
#endif
}

// wave-uniform float -> SGPR
static __device__ inline float sgpr_f(float x) {
  return __uint_as_float(__builtin_amdgcn_readfirstlane(__float_as_uint(x)));
}

// async global -> LDS, 16B per lane; LDS dest must be wave-uniform base
static __device__ inline void gl_lds16(const void* g, void* l) {
  __builtin_amdgcn_global_load_lds(
      (const __attribute__((address_space(1))) void*)g,
      (__attribute__((address_space(3))) void*)l, 16, 0, 0);
}

// ---------------- fused fp32 -> bf16 conversion of the 4 weight matrices ---------------
__global__ __launch_bounds__(256) void cvt4_kernel(const float* __restrict__ Wq,
                                                   const float* __restrict__ Wk,
                                                   const float* __restrict__ Wv,
                                                   const float* __restrict__ Wo,
                                                   u16* __restrict__ oq,
                                                   u16* __restrict__ ok,
                                                   u16* __restrict__ ov,
                                                   u16* __restrict__ oo) {
  int sel = blockIdx.x >> 8;
  int blk = blockIdx.x & 255;
  const float* in = (sel == 0) ? Wq : (sel == 1) ? Wk : (sel == 2) ? Wv : Wo;
  u16* out = (sel == 0) ? oq : (sel == 1) ? ok : (sel == 2) ? ov : oo;
  int i = (blk * 256 + threadIdx.x) * 4;
  float4 f = *reinterpret_cast<const float4*>(in + i);
  ushort4 o;
  o.x = f2bf(f.x); o.y = f2bf(f.y); o.z = f2bf(f.z); o.w = f2bf(f.w);
  *reinterpret_cast<ushort4*>(out + i) = o;
}

// ---------------- fused queries cvt (fp32->bf16) + spatial-reduce LayerNorm ------------
__global__ __launch_bounds__(256) void cvtln_kernel(const float* __restrict__ q,
                                                    const float* __restrict__ sr_w,
                                                    const float* __restrict__ sr_b,
                                                    const float* __restrict__ ln_w,
                                                    const float* __restrict__ ln_b,
                                                    u16* __restrict__ qbf,
                                                    u16* __restrict__ xln) {
  int w = blockIdx.x * 4 + (threadIdx.x >> 6);
  int lane = threadIdx.x & 63;
  if (w >= NB * NQ) {
    int w2 = w - NB * NQ;
    if (w2 < NB * 12) {
      int b = w2 / 12, pr = w2 % 12;
      u16* outp = xln + ((size_t)(b * NKP + NK + pr)) * DM;
      *reinterpret_cast<uint4*>(outp + lane * 8) = make_uint4(0u, 0u, 0u, 0u);
    }
    return;
  }
  int b = w / NQ, n = w % NQ;
  const float* row = q + ((size_t)w) * DM;
  int c0 = lane * 4, c1 = 256 + lane * 4;
  float4 x0 = *reinterpret_cast<const float4*>(row + c0);
  float4 x1 = *reinterpret_cast<const float4*>(row + c1);
  u16* qp = qbf + (size_t)w * DM;
  ushort4 q0, q1;
  q0.x = f2bf(x0.x); q0.y = f2bf(x0.y); q0.z = f2bf(x0.z); q0.w = f2bf(x0.w);
  q1.x = f2bf(x1.x); q1.y = f2bf(x1.y); q1.z = f2bf(x1.z); q1.w = f2bf(x1.w);
  *reinterpret_cast<ushort4*>(qp + c0) = q0;
  *reinterpret_cast<ushort4*>(qp + c1) = q1;
  int y = n / 28, x = n % 28;
  if ((y & 1) | (x & 1)) return;
  int np = (y >> 1) * 14 + (x >> 1);
  float4 w0 = *reinterpret_cast<const float4*>(sr_w + c0);
  float4 w1 = *reinterpret_cast<const float4*>(sr_w + c1);
  float4 s0 = *reinterpret_cast<const float4*>(sr_b + c0);
  float4 s1 = *reinterpret_cast<const float4*>(sr_b + c1);
  float yv[8];
  yv[0] = x0.x * w0.x + s0.x; yv[1] = x0.y * w0.y + s0.y;
  yv[2] = x0.z * w0.z + s0.z; yv[3] = x0.w * w0.w + s0.w;
  yv[4] = x1.x * w1.x + s1.x; yv[5] = x1.y * w1.y + s1.y;
  yv[6] = x1.z * w1.z + s1.z; yv[7] = x1.w * w1.w + s1.w;
  float s = 0.f, ss = 0.f;
  #pragma unroll
  for (int i = 0; i < 8; i++) { s += yv[i]; ss += yv[i] * yv[i]; }
  #pragma unroll
  for (int off = 1; off < 64; off <<= 1) {
    s += __shfl_xor(s, off); ss += __shfl_xor(ss, off);
  }
  float mu = s * (1.f / 512.f);
  float var = ss * (1.f / 512.f) - mu * mu;
  float rs = rsqrtf(var + 1e-5f);
  float4 lw0 = *reinterpret_cast<const float4*>(ln_w + c0);
  float4 lw1 = *reinterpret_cast<const float4*>(ln_w + c1);
  float4 lb0 = *reinterpret_cast<const float4*>(ln_b + c0);
  float4 lb1 = *reinterpret_cast<const float4*>(ln_b + c1);
  ushort4 o0, o1;
  o0.x = f2bf((yv[0] - mu) * rs * lw0.x + lb0.x);
  o0.y = f2bf((yv[1] - mu) * rs * lw0.y + lb0.y);
  o0.z = f2bf((yv[2] - mu) * rs * lw0.z + lb0.z);
  o0.w = f2bf((yv[3] - mu) * rs * lw0.w + lb0.w);
  o1.x = f2bf((yv[4] - mu) * rs * lw1.x + lb1.x);
  o1.y = f2bf((yv[5] - mu) * rs * lw1.y + lb1.y);
  o1.z = f2bf((yv[6] - mu) * rs * lw1.z + lb1.z);
  o1.w = f2bf((yv[7] - mu) * rs * lw1.w + lb1.w);
  u16* outp = xln + ((size_t)(b * NKP + np)) * DM;
  *reinterpret_cast<ushort4*>(outp + c0) = o0;
  *reinterpret_cast<ushort4*>(outp + c1) = o1;
}

// ---------------- shared GEMM body: C[M,512] = A[M,512]*W[512,512]^T + bias ------------
template <int OMODE>
static __device__ __forceinline__ void gemm_body(const u16* __restrict__ A,
                                                 const u16* __restrict__ Bw,
                                                 const float* __restrict__ bias,
                                                 void* __restrict__ Cptr,
                                                 int nt, int mt,
                                                 u16* Al0, u16* Al1,
                                                 u16* Bl0, u16* Bl1) {
  int wv = threadIdx.x >> 6, lane = threadIdx.x & 63;
  int lr = lane & 15, lg = lane >> 4;
  int wr = wv >> 1, wc = wv & 1;
  int row0 = mt * 128, col0 = nt * 128;

  auto stage = [&](int kk, int bi) {
    u16* Al = bi ? Al1 : Al0;
    u16* Bl = bi ? Bl1 : Bl0;
    #pragma unroll
    for (int i = 0; i < 4; i++) {
      int t = wv * 4 + i;                    // 0..15
      int rr = (t & 7) * 16 + (lane >> 2);
      int cc = lane & 3;
      if (t < 8) {
        gl_lds16(A + (size_t)(row0 + rr) * DM + kk + cc * 8, (char*)Al + t * 1024);
      } else {
        gl_lds16(Bw + (size_t)(col0 + rr) * DM + kk + cc * 8, (char*)Bl + (t - 8) * 1024);
      }
    }
  };

  f32x4 acc[4][4] = {};
  stage(0, 0);
  __syncthreads();
  for (int s = 0; s < 16; s++) {
    int bi = s & 1;
    if (s < 15) stage((s + 1) * 32, bi ^ 1);
    u16* Al = bi ? Al1 : Al0;
    u16* Bl = bi ? Bl1 : Bl0;
    bf16x8 am[4], bn[4];
    #pragma unroll
    for (int m = 0; m < 4; m++)
      am[m] = ld8(Al + (wr * 64 + m * 16 + lr) * 32 + lg * 8);
    #pragma unroll
    for (int n = 0; n < 4; n++)
      bn[n] = ld8(Bl + (wc * 64 + n * 16 + lr) * 32 + lg * 8);
    #pragma unroll
    for (int m = 0; m < 4; m++)
      #pragma unroll
      for (int n = 0; n < 4; n++)
        acc[m][n] = mfma16(am[m], bn[n], acc[m][n]);
    __syncthreads();
  }
  if (OMODE == 2) {
    #pragma unroll
    for (int n = 0; n < 4; n++) {
      int col = col0 + wc * 64 + n * 16 + lr;
      float bs = bias[col];
      #pragma unroll
      for (int m = 0; m < 4; m++) {
        int rbase = row0 + wr * 64 + m * 16 + lg * 4;
        int bb = rbase / NKP;
        int kr = rbase % NKP;          // kr&15 == lg*4
        ushort4 o4;
        o4.x = f2bf(acc[m][n][0] + bs);
        o4.y = f2bf(acc[m][n][1] + bs);
        o4.z = f2bf(acc[m][n][2] + bs);
        o4.w = f2bf(acc[m][n][3] + bs);
        size_t dst = (((size_t)bb * 13 + (kr >> 4)) * 512 + col) * 16 + (kr & 15);
        *reinterpret_cast<ushort4*>(&((u16*)Cptr)[dst]) = o4;
      }
    }
  } else {
    #pragma unroll
    for (int n = 0; n < 4; n++) {
      int col = col0 + wc * 64 + n * 16 + lr;
      float bs = bias[col];
      #pragma unroll
      for (int m = 0; m < 4; m++) {
        #pragma unroll
        for (int r = 0; r < 4; r++) {
          int row = row0 + wr * 64 + m * 16 + lg * 4 + r;
          float v = acc[m][n][r] + bs;
          if (OMODE == 0) {
            ((u16*)Cptr)[(size_t)row * DM + col] = f2bf(v);
          } else {
            ((float*)Cptr)[(size_t)row * DM + col] = v;
          }
        }
      }
    }
  }
}

// XCD-local decode: id = 32a + 8b + c  ->  nt = b, mt = c + 8a.
// Under round-robin dispatch (xcd = id % 8), XCD c processes only mt = c (mod 8)
// and runs the 4 nt of each mt back-to-back: every A-row-panel is fetched into
// exactly ONE XCD's L2 and stays hot (the dim3(4,M) grid spread each panel
// across 4 XCDs -> ~4x A re-fetch).
static __device__ inline void xcd_decode(int id, int& nt, int& mt) {
  nt = (id >> 3) & 3;
  mt = (id & 7) + 8 * (id >> 5);
}

// fused Q-proj [0,1568) + K-proj [1568,1984) + V-proj [1984,2400)
__global__ __launch_bounds__(256) void qkvgemm_kernel(
    const u16* __restrict__ qbf, const u16* __restrict__ Wq,
    const float* __restrict__ bq, void* __restrict__ Qout,
    const u16* __restrict__ xln, const u16* __restrict__ Wk,
    const float* __restrict__ bk, void* __restrict__ Kout,
    const u16* __restrict__ Wv, const float* __restrict__ bv,
    void* __restrict__ Vout) {
  __shared__ __align__(16) u16 Al[2][128 * 32];
  __shared__ __align__(16) u16 Bl[2][128 * 32];
  int id = blockIdx.x;
  int nt, mt;
  if (id < 1568) {
    xcd_decode(id, nt, mt);
    gemm_body<0>(qbf, Wq, bq, Qout, nt, mt,
                 &Al[0][0], &Al[1][0], &Bl[0][0], &Bl[1][0]);
  } else if (id < 1984) {
    xcd_decode(id - 1568, nt, mt);
    gemm_body<0>(xln, Wk, bk, Kout, nt, mt,
                 &Al[0][0], &Al[1][0], &Bl[0][0], &Bl[1][0]);
  } else {
    xcd_decode(id - 1984, nt, mt);
    gemm_body<2>(xln, Wv, bv, Vout, nt, mt,
                 &Al[0][0], &Al[1][0], &Bl[0][0], &Bl[1][0]);
  }
}

// O-proj (fp32 out), XCD-local 1-D grid
__global__ __launch_bounds__(256) void ogemm_kernel(const u16* __restrict__ A,
                                                    const u16* __restrict__ Bw,
                                                    const float* __restrict__ bias,
                                                    void* __restrict__ Cptr) {
  __shared__ __align__(16) u16 Al[2][128 * 32];
  __shared__ __align__(16) u16 Bl[2][128 * 32];
  int nt, mt;
  xcd_decode(blockIdx.x, nt, mt);
  gemm_body<1>(A, Bw, bias, Cptr, nt, mt,
               &Al[0][0], &Al[1][0], &Bl[0][0], &Bl[1][0]);
}

// ---------------- fused attn: 512 threads, 8 waves, ONE head per wave ------------------
// (unchanged from round 19: VGPR=64, occupancy 35%, 98us)
__global__ __launch_bounds__(512) void attn_kernel(const u16* __restrict__ Q,
                                                   const u16* __restrict__ K,
                                                   const u16* __restrict__ VTt,
                                                   const float* __restrict__ tw,
                                                   u16* __restrict__ Oat) {
  __shared__ __align__(16) u16 Kl[16 * 512];      // 16KB, chunk-major, single buf
  __shared__ __align__(16) float s2[2][16 * 256]; // 2 x 16KB, lane-order tiles
  int i = blockIdx.x;
  int g8 = i & 7;            // XCD group == b%8
  int j = i >> 3;            // 0..199
  int qc = j % 25;
  int b = g8 + 8 * (j / 25);
  int tid = threadIdx.x, wv = tid >> 6, lane = tid & 63;
  int lr = lane & 15, lg = lane >> 4;
  int q0A = qc * 32;
  int q0B = (qc < 24) ? (q0A + 16) : q0A;   // tail duplicates tile A
  // wave wv owns raw head wv AND output head wv

  const u16* Kb = K + (size_t)b * NKP * DM;
  const u16* Vtb = VTt + (size_t)b * 13 * 8192;

  // wave-uniform mixing weights for output head wv -> SGPRs (1/sqrt(64) folded)
  float w0[8];
  #pragma unroll
  for (int h = 0; h < 8; h++)
    w0[h] = sgpr_f(tw[wv * 8 + h] * 0.125f);

  // Q fragments REGISTER-resident: raw head wv x 2 tiles x 2 halves (16 VGPR)
  bf16x8 qr[2][2];   // [tile][half]
  #pragma unroll
  for (int t = 0; t < 2; t++) {
    const u16* Qb = Q + ((size_t)b * NQ + (t ? q0B : q0A)) * DM;
    qr[t][0] = ld8(Qb + (size_t)lr * DM + wv * 64 + lg * 8);
    qr[t][1] = ld8(Qb + (size_t)lr * DM + wv * 64 + 32 + lg * 8);
  }

  // chunk-major staging into the wave's PRIVATE eighth: groups g = wv*2, wv*2+1
  auto stageK = [&](int kt) {
    #pragma unroll
    for (int i2 = 0; i2 < 2; i2++) {
      int g = wv * 2 + i2;
      gl_lds16(Kb + (size_t)(kt * 16 + (lane & 15)) * DM + (g * 4 + (lane >> 4)) * 8,
               (char*)Kl + g * 1024);
    }
  };
  stageK(0);
  __syncthreads();

  f32x4 o[2][4] = {};      // [tile][j]
  float sumA = 0.f, sumB = 0.f;
  s16x4 vb[4];

  // mix + exp + PV for k-tile ktm, scores in s2[sbi]
  auto mixpv = [&](int ktm, int sbi) {
    bool masked = (ktm == 12) && (lg != 0);   // k >= 196
    s16x4 pa[2];
    #pragma unroll
    for (int t = 0; t < 2; t++) {
      f32x4 sa = {0.f, 0.f, 0.f, 0.f};
      #pragma unroll
      for (int h = 0; h < 8; h++) {
        f32x4 scv = *reinterpret_cast<const f32x4*>(
            &s2[sbi][0] + (t * 8 + h) * 256 + lane * 4);
        sa += scv * w0[h];
      }
      float e0 = masked ? 0.f : __expf(sa[0]);
      float e1 = masked ? 0.f : __expf(sa[1]);
      float e2 = masked ? 0.f : __expf(sa[2]);
      float e3 = masked ? 0.f : __expf(sa[3]);
      if (t == 0) sumA += (e0 + e1) + (e2 + e3);
      else        sumB += (e0 + e1) + (e2 + e3);
      union { __bf16 e[4]; s16x4 sv; } pk;
      pk.e[0] = (__bf16)e0; pk.e[1] = (__bf16)e1;
      pk.e[2] = (__bf16)e2; pk.e[3] = (__bf16)e3;
      pa[t] = pk.sv;
    }
    __builtin_amdgcn_s_setprio(1);
    #pragma unroll
    for (int t = 0; t < 2; t++) {
      #pragma unroll
      for (int j2 = 0; j2 < 4; j2++)
        o[t][j2] = mfma16k16(pa[t], vb[j2], o[t][j2]);
    }
    __builtin_amdgcn_s_setprio(0);
  };

  for (int kt = 0; kt < 13; kt++) {
    int bi = kt & 1;

    // EARLY V for the pipelined mix/PV of kt-1 (latency hidden under QK^T)
    if (kt > 0) {
      #pragma unroll
      for (int j2 = 0; j2 < 4; j2++) {
        int d = wv * 64 + j2 * 16 + lr;
        vb[j2] = *reinterpret_cast<const s16x4*>(
            Vtb + (size_t)(kt - 1) * 8192 + d * 16 + lg * 4);
      }
    }

    // QK^T(kt) for raw head wv, both tiles; write s2[bi]
    const u16* kbase = Kl + lg * 128 + lr * 8;
    __builtin_amdgcn_s_setprio(1);
    {
      bf16x8 kf0 = ld8(kbase + wv * 1024);
      bf16x8 kf1 = ld8(kbase + wv * 1024 + 512);
      #pragma unroll
      for (int t = 0; t < 2; t++) {
        f32x4 tt = {0.f, 0.f, 0.f, 0.f};
        tt = mfma16(kf0, qr[t][0], tt);
        tt = mfma16(kf1, qr[t][1], tt);
        *reinterpret_cast<f32x4*>(&s2[bi][0] + (t * 8 + wv) * 256 + lane * 4) = tt;
      }
    }
    __builtin_amdgcn_s_setprio(0);

    // fence: all kf ds_reads retired before this wave overwrites its eighth
    asm volatile("s_waitcnt lgkmcnt(0)" ::: "memory");
    __builtin_amdgcn_sched_barrier(0);
    if (kt < 12) stageK(kt + 1);

    // pipelined mix/exp/PV for kt-1 (scores from s2[bi^1])
    if (kt > 0) mixpv(kt - 1, bi ^ 1);

    __syncthreads();   // drains stage(kt+1) writes; s2[bi] visible for iter kt+1
  }
  // epilogue: mix/PV for kt=12 (scores in s2[0], visible after last barrier)
  {
    #pragma unroll
    for (int j2 = 0; j2 < 4; j2++) {
      int d = wv * 64 + j2 * 16 + lr;
      vb[j2] = *reinterpret_cast<const s16x4*>(
          Vtb + (size_t)12 * 8192 + d * 16 + lg * 4);
    }
    mixpv(12, 0);
  }

  // complete row sums (k split across lane groups 16 apart)
  sumA += __shfl_xor(sumA, 16); sumA += __shfl_xor(sumA, 32);
  sumB += __shfl_xor(sumB, 16); sumB += __shfl_xor(sumB, 32);
  float ivA = 1.0f / sumA, ivB = 1.0f / sumB;
  #pragma unroll
  for (int t = 0; t < 2; t++) {
    if (t == 1 && qc == 24) break;   // tail: tile B is a duplicate
    int q0 = t ? q0B : q0A;
    float ivsrc = t ? ivB : ivA;
    #pragma unroll
    for (int r = 0; r < 4; r++) {
      int q = lg * 4 + r;
      float iv = __shfl(ivsrc, q);   // sum lives at lane lr == q
      #pragma unroll
      for (int j2 = 0; j2 < 4; j2++) {
        Oat[((size_t)(b * NQ + q0 + q)) * DM + wv * 64 + j2 * 16 + lr] =
            f2bf(o[t][j2][r] * iv);
      }
    }
  }
}

// ---------------- launch ----------------
extern "C" void kernel_launch(void* const* d_in, const int* in_sizes, int n_in,
                              void* d_out, int out_size, void* d_ws, size_t ws_size,
                              hipStream_t stream) {
  const float* queries = (const float*)d_in[0];
  const float* Wq = (const float*)d_in[3];
  const float* bq = (const float*)d_in[4];
  const float* Wk = (const float*)d_in[5];
  const float* bk = (const float*)d_in[6];
  const float* Wv = (const float*)d_in[7];
  const float* bv = (const float*)d_in[8];
  const float* Wo = (const float*)d_in[9];
  const float* bo = (const float*)d_in[10];
  const float* sr_w = (const float*)d_in[11];
  const float* sr_b = (const float*)d_in[12];
  const float* ln_w = (const float*)d_in[13];
  const float* ln_b = (const float*)d_in[14];
  const float* tw = (const float*)d_in[15];

  char* ws = (char*)d_ws;
  u16* wq_bf = (u16*)(ws + 0);          // 512KB
  u16* wk_bf = (u16*)(ws + 524288);
  u16* wv_bf = (u16*)(ws + 1048576);
  u16* wo_bf = (u16*)(ws + 1572864);
  u16* xln   = (u16*)(ws + 2097152);    // 64*208*512*2 = 13,631,488
  u16* Kbuf  = (u16*)(ws + 15728640);   // 13,631,488
  u16* VTt   = (u16*)(ws + 29360128);   // 64*13*512*16*2 = 13,631,488
  u16* Qbuf  = (u16*)(ws + 42991616);   // 64*784*512*2 = 51,380,224
  u16* qbf   = (u16*)(ws + 94371840);   // 51,380,224 -> end 145,752,064
  u16* Oat   = qbf;                     // qbf dead after Q-proj; attn reuses it
  if (ws_size < 145752064u) return;     // fail loudly (output stays poisoned)

  // all 4 weight conversions in ONE launch (1024 blocks)
  cvt4_kernel<<<1024, 256, 0, stream>>>(Wq, Wk, Wv, Wo,
                                        wq_bf, wk_bf, wv_bf, wo_bf);

  // fused queries cvt + LN: 64*784 + 64*12 waves
  cvtln_kernel<<<(NB * NQ + NB * 12 + 3) / 4, 256, 0, stream>>>(
      queries, sr_w, sr_b, ln_w, ln_b, qbf, xln);

  // Q-proj + K-proj + V-proj in ONE launch, XCD-local A-panels
  qkvgemm_kernel<<<2400, 256, 0, stream>>>(qbf, wq_bf, bq, Qbuf,
                                           xln, wk_bf, bk, Kbuf,
                                           wv_bf, bv, VTt);

  attn_kernel<<<dim3(1600), 512, 0, stream>>>(Qbuf, Kbuf, VTt, tw, Oat);

  // out = Oat @ Wo^T + bo  (fp32 out), XCD-local A-panels
  ogemm_kernel<<<1568, 256, 0, stream>>>(Oat, wo_bf, bo, d_out);
}